// Round 5
// baseline (847.328 us; speedup 1.0000x reference)
//
#include <hip/hip_runtime.h>

#define NFEAT 128
#define NHID  64
#define NCLS  32
#define NW    64        // histogram-owning workgroups (8/XCD x 400KB = 3.2MB of L2)

// ---- pass A: per-WG private histogram (WG-scope atomics, L2-resident) --
// also computes ew and the WG-local rank of each edge within its bucket.
__global__ __launch_bounds__(256) void k_hist(const int* __restrict__ colv,
                                              const float* __restrict__ A0,
                                              const float* __restrict__ A1,
                                              const float* __restrict__ wsv,
                                              float* __restrict__ ew_out,
                                              int* __restrict__ rank_out,
                                              int* __restrict__ hist,
                                              int N, int E, int epw) {
    int w = blockIdx.x;
    int* mh = hist + (size_t)w * N;
    for (int i = threadIdx.x; i < N; i += 256) mh[i] = 0;
    __syncthreads();
    int e0 = w * epw;
    int e1 = min(E, e0 + epw);
    float ws0 = wsv[0], ws1 = wsv[1];
    for (int e = e0 + threadIdx.x; e < e1; e += 256) {
        float a0 = __builtin_nontemporal_load(&A0[e]);
        float a1 = __builtin_nontemporal_load(&A1[e]);
        int   c  = __builtin_nontemporal_load(&colv[e]);
        float ew = fmaf(ws0, a0, ws1 * a1);
        __builtin_nontemporal_store(ew, &ew_out[e]);
        int rk = __hip_atomic_fetch_add(&mh[c], 1, __ATOMIC_RELAXED,
                                        __HIP_MEMORY_SCOPE_WORKGROUP);
        __builtin_nontemporal_store(rk, &rank_out[e]);
    }
}

// ---- scan phase 1 (fused column-sum): colsum[n] = sum_w hist[w][n] -----
__global__ void k_scan1(const int* __restrict__ hist, int* __restrict__ colsum,
                        int* bsum, int N) {
    __shared__ int lds[256];
    int t = threadIdx.x, b = blockIdx.x;
    int base = b * 1024 + t * 4;
    int s = 0;
#pragma unroll
    for (int i = 0; i < 4; i++) {
        int idx = base + i;
        if (idx < N) {
            int c = 0;
            for (int w = 0; w < NW; w++) c += hist[(size_t)w * N + idx];
            colsum[idx] = c;
            s += c;
        }
    }
    lds[t] = s; __syncthreads();
    for (int off = 128; off > 0; off >>= 1) { if (t < off) lds[t] += lds[t + off]; __syncthreads(); }
    if (t == 0) bsum[b] = lds[0];
}

__global__ void k_scan2(int* bsum, int NB) {
    __shared__ int lds[128];
    int t = threadIdx.x;
    int v = (t < NB) ? bsum[t] : 0;
    lds[t] = v; __syncthreads();
    for (int off = 1; off < 128; off <<= 1) {
        int y = (t >= off) ? lds[t - off] : 0;
        __syncthreads();
        lds[t] += y;
        __syncthreads();
    }
    if (t < NB) bsum[t] = lds[t] - v;   // exclusive
}

// ---- scan phase 3 + base distribution: rowptr + per-WG bucket bases ----
// hist[w][n] (count) is replaced in place by its global base offset:
// rowptr[n] + sum_{w'<w} hist[w'][n].
__global__ void k_scan3(const int* __restrict__ colsum, const int* __restrict__ bsum,
                        int* rowptr, int* __restrict__ hist, int N, int E) {
    __shared__ int lds[256];
    int t = threadIdx.x, b = blockIdx.x;
    int base = b * 1024 + t * 4;
    int v[4]; int s = 0;
#pragma unroll
    for (int i = 0; i < 4; i++) { int idx = base + i; v[i] = (idx < N) ? colsum[idx] : 0; s += v[i]; }
    lds[t] = s; __syncthreads();
    for (int off = 1; off < 256; off <<= 1) {
        int y = (t >= off) ? lds[t - off] : 0;
        __syncthreads();
        lds[t] += y;
        __syncthreads();
    }
    int run = lds[t] - s + bsum[b];
#pragma unroll
    for (int i = 0; i < 4; i++) {
        int idx = base + i;
        if (idx < N) {
            rowptr[idx] = run;
            int running = run;
            for (int w = 0; w < NW; w++) {
                size_t o = (size_t)w * N + idx;
                int tt = hist[o];
                hist[o] = running;
                running += tt;
            }
        }
        run += v[i];
    }
    if (b == 0 && t == 0) rowptr[N] = E;
}

// ---- CSR fill (atomic-free): csr[base[wg][col] + rank] = {src, ew} -----
__global__ void k_fill(const int* __restrict__ rowv, const int* __restrict__ colv,
                       const float* __restrict__ ew_in, const int* __restrict__ rank,
                       const int* __restrict__ hist, int2* __restrict__ csr,
                       int N, int E, int epw) {
    int e = blockIdx.x * blockDim.x + threadIdx.x;
    if (e >= E) return;
    int c  = __builtin_nontemporal_load(&colv[e]);
    int r  = __builtin_nontemporal_load(&rowv[e]);
    float w = __builtin_nontemporal_load(&ew_in[e]);
    int rk = __builtin_nontemporal_load(&rank[e]);
    int wg = e / epw;
    int pos = hist[(size_t)wg * N + c] + rk;
    csr[pos] = make_int2(r, __float_as_int(w));
}

// ---- dinv[n] = rsqrt(1 + sum of bucket ew) — coalesced gather ----------
__global__ __launch_bounds__(256) void k_deg(const int2* __restrict__ csr,
                                             const int* __restrict__ rowptr,
                                             float* __restrict__ dinv, int N) {
    int t = threadIdx.x;
    int lane = t & 63;
    int n = blockIdx.x * 4 + (t >> 6);
    if (n >= N) return;
    int e0 = rowptr[n], e1 = rowptr[n + 1];
    float s = 0.f;
    for (int e = e0 + lane; e < e1; e += 64) s += __int_as_float(csr[e].y);
#pragma unroll
    for (int off = 1; off < 64; off <<= 1) s += __shfl_xor(s, off, 64);
    if (lane == 0) dinv[n] = rsqrtf(1.0f + s);
}

// ---- GEMM1 + dinv scale: h0' = dinv[r] * (x @ W1) ----------------------
__global__ __launch_bounds__(256) void k_gemm1(const float* __restrict__ x,
                                               const float* __restrict__ W1,
                                               const float* __restrict__ dinv,
                                               float* __restrict__ h0, int N) {
    __shared__ float w[NFEAT * NHID];   // 32 KB
    int t = threadIdx.x;
    const float4* W4 = (const float4*)W1;
    float4* w4 = (float4*)w;
#pragma unroll
    for (int i = 0; i < 8; i++) w4[t + 256 * i] = W4[t + 256 * i];
    __syncthreads();
    int wave = t >> 6, lane = t & 63;
    int r0 = blockIdx.x * 32 + wave * 8;
    for (int i = 0; i < 8; i++) {
        int r = r0 + i;
        if (r >= N) break;
        const float4* xr = (const float4*)(x + (size_t)r * NFEAT);
        float acc = 0.f;
#pragma unroll
        for (int k4 = 0; k4 < 32; k4++) {
            float4 xv = xr[k4];
            int k = k4 * 4;
            acc = fmaf(xv.x, w[(k + 0) * 64 + lane], acc);
            acc = fmaf(xv.y, w[(k + 1) * 64 + lane], acc);
            acc = fmaf(xv.z, w[(k + 2) * 64 + lane], acc);
            acc = fmaf(xv.w, w[(k + 3) * 64 + lane], acc);
        }
        h0[(size_t)r * 64 + lane] = acc * dinv[r];
    }
}

// ---- agg1 + relu: h = relu(di*(Agg + self) + b1), unroll x4 ------------
__global__ __launch_bounds__(256) void k_agg1(const float* __restrict__ h0,
                                              const int* __restrict__ rowptr,
                                              const int2* __restrict__ csr,
                                              const float* __restrict__ dinv,
                                              const float* __restrict__ b1,
                                              float* __restrict__ h, int N) {
    int t = threadIdx.x;
    int lane = t & 63;
    int n = blockIdx.x * 4 + (t >> 6);
    if (n >= N) return;
    int g = lane >> 4;
    int l = lane & 15;
    int e0 = rowptr[n], e1 = rowptr[n + 1];
    float4 a0 = make_float4(0.f, 0.f, 0.f, 0.f);
    float4 a1 = make_float4(0.f, 0.f, 0.f, 0.f);
    float4 a2 = make_float4(0.f, 0.f, 0.f, 0.f);
    float4 a3 = make_float4(0.f, 0.f, 0.f, 0.f);
    int e = e0 + g;
    for (; e + 12 < e1; e += 16) {
        int2 c0 = csr[e];
        int2 c1 = csr[e + 4];
        int2 c2 = csr[e + 8];
        int2 c3 = csr[e + 12];
        float4 v0 = ((const float4*)(h0 + (size_t)c0.x * NHID))[l];
        float4 v1 = ((const float4*)(h0 + (size_t)c1.x * NHID))[l];
        float4 v2 = ((const float4*)(h0 + (size_t)c2.x * NHID))[l];
        float4 v3 = ((const float4*)(h0 + (size_t)c3.x * NHID))[l];
        float w0 = __int_as_float(c0.y), w1 = __int_as_float(c1.y);
        float w2 = __int_as_float(c2.y), w3 = __int_as_float(c3.y);
        a0.x = fmaf(w0, v0.x, a0.x); a0.y = fmaf(w0, v0.y, a0.y);
        a0.z = fmaf(w0, v0.z, a0.z); a0.w = fmaf(w0, v0.w, a0.w);
        a1.x = fmaf(w1, v1.x, a1.x); a1.y = fmaf(w1, v1.y, a1.y);
        a1.z = fmaf(w1, v1.z, a1.z); a1.w = fmaf(w1, v1.w, a1.w);
        a2.x = fmaf(w2, v2.x, a2.x); a2.y = fmaf(w2, v2.y, a2.y);
        a2.z = fmaf(w2, v2.z, a2.z); a2.w = fmaf(w2, v2.w, a2.w);
        a3.x = fmaf(w3, v3.x, a3.x); a3.y = fmaf(w3, v3.y, a3.y);
        a3.z = fmaf(w3, v3.z, a3.z); a3.w = fmaf(w3, v3.w, a3.w);
    }
    for (; e < e1; e += 4) {
        int2 c0 = csr[e];
        float4 v0 = ((const float4*)(h0 + (size_t)c0.x * NHID))[l];
        float w0 = __int_as_float(c0.y);
        a0.x = fmaf(w0, v0.x, a0.x); a0.y = fmaf(w0, v0.y, a0.y);
        a0.z = fmaf(w0, v0.z, a0.z); a0.w = fmaf(w0, v0.w, a0.w);
    }
    a0.x += a1.x + a2.x + a3.x;
    a0.y += a1.y + a2.y + a3.y;
    a0.z += a1.z + a2.z + a3.z;
    a0.w += a1.w + a2.w + a3.w;
#pragma unroll
    for (int off = 16; off < 64; off <<= 1) {
        a0.x += __shfl_xor(a0.x, off, 64);
        a0.y += __shfl_xor(a0.y, off, 64);
        a0.z += __shfl_xor(a0.z, off, 64);
        a0.w += __shfl_xor(a0.w, off, 64);
    }
    if (lane < 16) {
        float di = dinv[n];
        float4 sv = ((const float4*)(h0 + (size_t)n * NHID))[l];
        float4 bv = ((const float4*)b1)[l];
        float4 r;
        r.x = fmaxf(fmaf(di, a0.x + sv.x, bv.x), 0.f);
        r.y = fmaxf(fmaf(di, a0.y + sv.y, bv.y), 0.f);
        r.z = fmaxf(fmaf(di, a0.z + sv.z, bv.z), 0.f);
        r.w = fmaxf(fmaf(di, a0.w + sv.w, bv.w), 0.f);
        ((float4*)(h + (size_t)n * NHID))[l] = r;
    }
}

// ---- GEMM2 + dinv scale: h2' = dinv[r] * (h @ W2) ----------------------
__global__ __launch_bounds__(256) void k_gemm2(const float* __restrict__ h,
                                               const float* __restrict__ W2,
                                               const float* __restrict__ dinv,
                                               float* __restrict__ h2, int N) {
    __shared__ float w[NHID * NCLS];    // 8 KB
    int t = threadIdx.x;
    const float4* W4 = (const float4*)W2;
    float4* w4 = (float4*)w;
    w4[t] = W4[t];
    if (t < 256) w4[t + 256] = W4[t + 256];
    __syncthreads();
    int wave = t >> 6, lane = t & 63;
    int rsub = lane >> 5, j = lane & 31;
    int r0 = blockIdx.x * 64 + wave * 16 + rsub;
    for (int i = 0; i < 8; i++) {
        int r = r0 + i * 2;
        if (r >= N) continue;
        const float4* hr = (const float4*)(h + (size_t)r * 64);
        float acc = 0.f;
#pragma unroll
        for (int k4 = 0; k4 < 16; k4++) {
            float4 hv = hr[k4];
            int k = k4 * 4;
            acc = fmaf(hv.x, w[(k + 0) * 32 + j], acc);
            acc = fmaf(hv.y, w[(k + 1) * 32 + j], acc);
            acc = fmaf(hv.z, w[(k + 2) * 32 + j], acc);
            acc = fmaf(hv.w, w[(k + 3) * 32 + j], acc);
        }
        h2[(size_t)r * 32 + j] = acc * dinv[r];
    }
}

// ---- agg2: out = di*(Agg + self) + b2, unroll x4 -----------------------
__global__ __launch_bounds__(256) void k_agg2(const float* __restrict__ h2,
                                              const int* __restrict__ rowptr,
                                              const int2* __restrict__ csr,
                                              const float* __restrict__ dinv,
                                              const float* __restrict__ b2,
                                              float* __restrict__ out, int N) {
    int t = threadIdx.x;
    int lane = t & 63;
    int n = blockIdx.x * 4 + (t >> 6);
    if (n >= N) return;
    int g = lane >> 3;
    int l = lane & 7;
    int e0 = rowptr[n], e1 = rowptr[n + 1];
    float4 a0 = make_float4(0.f, 0.f, 0.f, 0.f);
    float4 a1 = make_float4(0.f, 0.f, 0.f, 0.f);
    float4 a2 = make_float4(0.f, 0.f, 0.f, 0.f);
    float4 a3 = make_float4(0.f, 0.f, 0.f, 0.f);
    int e = e0 + g;
    for (; e + 24 < e1; e += 32) {
        int2 c0 = csr[e];
        int2 c1 = csr[e + 8];
        int2 c2 = csr[e + 16];
        int2 c3 = csr[e + 24];
        float4 v0 = ((const float4*)(h2 + (size_t)c0.x * NCLS))[l];
        float4 v1 = ((const float4*)(h2 + (size_t)c1.x * NCLS))[l];
        float4 v2 = ((const float4*)(h2 + (size_t)c2.x * NCLS))[l];
        float4 v3 = ((const float4*)(h2 + (size_t)c3.x * NCLS))[l];
        float w0 = __int_as_float(c0.y), w1 = __int_as_float(c1.y);
        float w2 = __int_as_float(c2.y), w3 = __int_as_float(c3.y);
        a0.x = fmaf(w0, v0.x, a0.x); a0.y = fmaf(w0, v0.y, a0.y);
        a0.z = fmaf(w0, v0.z, a0.z); a0.w = fmaf(w0, v0.w, a0.w);
        a1.x = fmaf(w1, v1.x, a1.x); a1.y = fmaf(w1, v1.y, a1.y);
        a1.z = fmaf(w1, v1.z, a1.z); a1.w = fmaf(w1, v1.w, a1.w);
        a2.x = fmaf(w2, v2.x, a2.x); a2.y = fmaf(w2, v2.y, a2.y);
        a2.z = fmaf(w2, v2.z, a2.z); a2.w = fmaf(w2, v2.w, a2.w);
        a3.x = fmaf(w3, v3.x, a3.x); a3.y = fmaf(w3, v3.y, a3.y);
        a3.z = fmaf(w3, v3.z, a3.z); a3.w = fmaf(w3, v3.w, a3.w);
    }
    for (; e < e1; e += 8) {
        int2 c0 = csr[e];
        float4 v0 = ((const float4*)(h2 + (size_t)c0.x * NCLS))[l];
        float w0 = __int_as_float(c0.y);
        a0.x = fmaf(w0, v0.x, a0.x); a0.y = fmaf(w0, v0.y, a0.y);
        a0.z = fmaf(w0, v0.z, a0.z); a0.w = fmaf(w0, v0.w, a0.w);
    }
    a0.x += a1.x + a2.x + a3.x;
    a0.y += a1.y + a2.y + a3.y;
    a0.z += a1.z + a2.z + a3.z;
    a0.w += a1.w + a2.w + a3.w;
#pragma unroll
    for (int off = 8; off < 64; off <<= 1) {
        a0.x += __shfl_xor(a0.x, off, 64);
        a0.y += __shfl_xor(a0.y, off, 64);
        a0.z += __shfl_xor(a0.z, off, 64);
        a0.w += __shfl_xor(a0.w, off, 64);
    }
    if (lane < 8) {
        float di = dinv[n];
        float4 sv = ((const float4*)(h2 + (size_t)n * NCLS))[l];
        float4 bv = ((const float4*)b2)[l];
        float4 r;
        r.x = fmaf(di, a0.x + sv.x, bv.x);
        r.y = fmaf(di, a0.y + sv.y, bv.y);
        r.z = fmaf(di, a0.z + sv.z, bv.z);
        r.w = fmaf(di, a0.w + sv.w, bv.w);
        ((float4*)(out + (size_t)n * NCLS))[l] = r;
    }
}

extern "C" void kernel_launch(void* const* d_in, const int* in_sizes, int n_in,
                              void* d_out, int out_size, void* d_ws, size_t ws_size,
                              hipStream_t stream) {
    const float* x   = (const float*)d_in[0];
    const int*   ei  = (const int*)d_in[1];     // [2, E] int32
    const float* A0  = (const float*)d_in[2];
    const float* A1  = (const float*)d_in[3];
    const float* wsv = (const float*)d_in[4];
    const float* W1  = (const float*)d_in[5];
    const float* b1  = (const float*)d_in[6];
    const float* W2  = (const float*)d_in[7];
    const float* b2  = (const float*)d_in[8];
    float* out = (float*)d_out;

    int N = in_sizes[0] / NFEAT;    // 100000
    int E = in_sizes[1] / 2;        // 3200000
    const int* rowv = ei;           // source
    const int* colv = ei + E;       // target

    char* p = (char*)d_ws;
    auto alloc = [&](size_t bytes) -> void* {
        void* q = (void*)p; p += (bytes + 255) & ~(size_t)255; return q;
    };
    float* dinv    = (float*)alloc((size_t)N * 4);
    int*   colsum  = (int*)  alloc((size_t)N * 4);
    int*   rowptr  = (int*)  alloc((size_t)(N + 1) * 4);
    int*   bsum    = (int*)  alloc(1024 * 4);
    float* ew      = (float*)alloc((size_t)E * 4);
    int*   rank    = (int*)  alloc((size_t)E * 4);
    int2*  csr     = (int2*) alloc((size_t)E * 8);
    int*   hist    = (int*)  alloc((size_t)NW * N * 4);     // 25.6 MB
    float* h0      = (float*)alloc((size_t)N * NHID * 4);
    float* h       = (float*)alloc((size_t)N * NHID * 4);
    float* h2      = h0;            // reuse: h0 dead after agg1

    int NB = (N + 1023) / 1024;     // 98 (<=128 required by k_scan2)
    int epw = (E + NW - 1) / NW;    // 50000 edges per histogram WG

    k_hist<<<NW, 256, 0, stream>>>(colv, A0, A1, wsv, ew, rank, hist, N, E, epw);
    k_scan1<<<NB, 256, 0, stream>>>(hist, colsum, bsum, N);
    k_scan2<<<1, 128, 0, stream>>>(bsum, NB);
    k_scan3<<<NB, 256, 0, stream>>>(colsum, bsum, rowptr, hist, N, E);
    k_fill<<<(E + 255) / 256, 256, 0, stream>>>(rowv, colv, ew, rank, hist, csr, N, E, epw);
    k_deg<<<(N + 3) / 4, 256, 0, stream>>>(csr, rowptr, dinv, N);
    k_gemm1<<<(N + 31) / 32, 256, 0, stream>>>(x, W1, dinv, h0, N);
    k_agg1<<<(N + 3) / 4, 256, 0, stream>>>(h0, rowptr, csr, dinv, b1, h, N);
    k_gemm2<<<(N + 63) / 64, 256, 0, stream>>>(h, W2, dinv, h2, N);
    k_agg2<<<(N + 3) / 4, 256, 0, stream>>>(h2, rowptr, csr, dinv, b2, out, N);
}

// Round 6
// 712.922 us; speedup vs baseline: 1.1885x; 1.1885x over previous
//
#include <hip/hip_runtime.h>

#define NFEAT 128
#define NHID  64
#define NCLS  32
#define NC    64        // edge chunks (hist slices)
#define RNG   16384     // node-range per LDS histogram (64 KB)

// ---- pass A: LDS-privatized histogram + rank --------------------------
// WG (c, r): stream edge chunk c, count cols in node range r via LDS
// atomics (ds_add_rtn). rank_out[e] = local rank within (chunk, bucket).
__global__ __launch_bounds__(256) void k_hist(const int* __restrict__ colv,
                                              int* __restrict__ rank_out,
                                              int* __restrict__ hist,
                                              int N, int E, int epc) {
    __shared__ int lh[RNG];
    int c = blockIdx.x;
    int r = blockIdx.y;
    int base = r * RNG;
    int lim = min(RNG, N - base);
    for (int i = threadIdx.x; i < RNG; i += 256) lh[i] = 0;
    __syncthreads();
    int e0 = c * epc, e1 = min(E, e0 + epc);
    for (int e = e0 + threadIdx.x; e < e1; e += 256) {
        int off = colv[e] - base;
        if ((unsigned)off < (unsigned)RNG) {
            rank_out[e] = atomicAdd(&lh[off], 1);
        }
    }
    __syncthreads();
    int* gh = hist + (size_t)c * N + base;
    for (int i = threadIdx.x; i < lim; i += 256) gh[i] = lh[i];
}

// ---- scan phase 1 (fused column-sum): colsum[n] = sum_c hist[c][n] -----
__global__ void k_scan1(const int* __restrict__ hist, int* __restrict__ colsum,
                        int* bsum, int N) {
    __shared__ int lds[256];
    int t = threadIdx.x, b = blockIdx.x;
    int base = b * 1024 + t * 4;
    int s = 0;
#pragma unroll
    for (int i = 0; i < 4; i++) {
        int idx = base + i;
        if (idx < N) {
            int cs = 0;
            for (int w = 0; w < NC; w++) cs += hist[(size_t)w * N + idx];
            colsum[idx] = cs;
            s += cs;
        }
    }
    lds[t] = s; __syncthreads();
    for (int off = 128; off > 0; off >>= 1) { if (t < off) lds[t] += lds[t + off]; __syncthreads(); }
    if (t == 0) bsum[b] = lds[0];
}

__global__ void k_scan2(int* bsum, int NB) {
    __shared__ int lds[128];
    int t = threadIdx.x;
    int v = (t < NB) ? bsum[t] : 0;
    lds[t] = v; __syncthreads();
    for (int off = 1; off < 128; off <<= 1) {
        int y = (t >= off) ? lds[t - off] : 0;
        __syncthreads();
        lds[t] += y;
        __syncthreads();
    }
    if (t < NB) bsum[t] = lds[t] - v;   // exclusive
}

// ---- scan phase 3: rowptr + distribute per-chunk bases into hist -------
__global__ void k_scan3(const int* __restrict__ colsum, const int* __restrict__ bsum,
                        int* rowptr, int* __restrict__ hist, int N, int E) {
    __shared__ int lds[256];
    int t = threadIdx.x, b = blockIdx.x;
    int base = b * 1024 + t * 4;
    int v[4]; int s = 0;
#pragma unroll
    for (int i = 0; i < 4; i++) { int idx = base + i; v[i] = (idx < N) ? colsum[idx] : 0; s += v[i]; }
    lds[t] = s; __syncthreads();
    for (int off = 1; off < 256; off <<= 1) {
        int y = (t >= off) ? lds[t - off] : 0;
        __syncthreads();
        lds[t] += y;
        __syncthreads();
    }
    int run = lds[t] - s + bsum[b];
#pragma unroll
    for (int i = 0; i < 4; i++) {
        int idx = base + i;
        if (idx < N) {
            rowptr[idx] = run;
            int running = run;
            for (int w = 0; w < NC; w++) {
                size_t o = (size_t)w * N + idx;
                int tt = hist[o];
                hist[o] = running;
                running += tt;
            }
        }
        run += v[i];
    }
    if (b == 0 && t == 0) rowptr[N] = E;
}

// ---- CSR fill (atomic-free): csr[hist[c][col] + rank] = {src, ew} ------
__global__ void k_fill(const int* __restrict__ rowv, const int* __restrict__ colv,
                       const float* __restrict__ A0, const float* __restrict__ A1,
                       const float* __restrict__ wsv, const int* __restrict__ rank,
                       const int* __restrict__ hist, int2* __restrict__ csr,
                       int N, int E, int epc) {
    int e = blockIdx.x * blockDim.x + threadIdx.x;
    if (e >= E) return;
    int c = colv[e];
    float ewv = fmaf(wsv[0], A0[e], wsv[1] * A1[e]);
    int wg = e / epc;
    int pos = hist[(size_t)wg * N + c] + rank[e];
    csr[pos] = make_int2(rowv[e], __float_as_int(ewv));
}

// ---- dinv[n] = rsqrt(1 + sum of bucket ew) — coalesced gather ----------
__global__ __launch_bounds__(256) void k_deg(const int2* __restrict__ csr,
                                             const int* __restrict__ rowptr,
                                             float* __restrict__ dinv, int N) {
    int t = threadIdx.x;
    int lane = t & 63;
    int n = blockIdx.x * 4 + (t >> 6);
    if (n >= N) return;
    int e0 = rowptr[n], e1 = rowptr[n + 1];
    float s = 0.f;
    for (int e = e0 + lane; e < e1; e += 64) s += __int_as_float(csr[e].y);
#pragma unroll
    for (int off = 1; off < 64; off <<= 1) s += __shfl_xor(s, off, 64);
    if (lane == 0) dinv[n] = rsqrtf(1.0f + s);
}

// ---- GEMM1 + dinv scale: h0' = dinv[r] * (x @ W1) ----------------------
__global__ __launch_bounds__(256) void k_gemm1(const float* __restrict__ x,
                                               const float* __restrict__ W1,
                                               const float* __restrict__ dinv,
                                               float* __restrict__ h0, int N) {
    __shared__ float w[NFEAT * NHID];   // 32 KB
    int t = threadIdx.x;
    const float4* W4 = (const float4*)W1;
    float4* w4 = (float4*)w;
#pragma unroll
    for (int i = 0; i < 8; i++) w4[t + 256 * i] = W4[t + 256 * i];
    __syncthreads();
    int wave = t >> 6, lane = t & 63;
    int r0 = blockIdx.x * 32 + wave * 8;
    for (int i = 0; i < 8; i++) {
        int r = r0 + i;
        if (r >= N) break;
        const float4* xr = (const float4*)(x + (size_t)r * NFEAT);
        float acc = 0.f;
#pragma unroll
        for (int k4 = 0; k4 < 32; k4++) {
            float4 xv = xr[k4];
            int k = k4 * 4;
            acc = fmaf(xv.x, w[(k + 0) * 64 + lane], acc);
            acc = fmaf(xv.y, w[(k + 1) * 64 + lane], acc);
            acc = fmaf(xv.z, w[(k + 2) * 64 + lane], acc);
            acc = fmaf(xv.w, w[(k + 3) * 64 + lane], acc);
        }
        h0[(size_t)r * 64 + lane] = acc * dinv[r];
    }
}

// ---- agg1 + relu: h = relu(di*(Agg + self) + b1), unroll x4 ------------
__global__ __launch_bounds__(256) void k_agg1(const float* __restrict__ h0,
                                              const int* __restrict__ rowptr,
                                              const int2* __restrict__ csr,
                                              const float* __restrict__ dinv,
                                              const float* __restrict__ b1,
                                              float* __restrict__ h, int N) {
    int t = threadIdx.x;
    int lane = t & 63;
    int n = blockIdx.x * 4 + (t >> 6);
    if (n >= N) return;
    int g = lane >> 4;
    int l = lane & 15;
    int e0 = rowptr[n], e1 = rowptr[n + 1];
    float4 a0 = make_float4(0.f, 0.f, 0.f, 0.f);
    float4 a1 = make_float4(0.f, 0.f, 0.f, 0.f);
    float4 a2 = make_float4(0.f, 0.f, 0.f, 0.f);
    float4 a3 = make_float4(0.f, 0.f, 0.f, 0.f);
    int e = e0 + g;
    for (; e + 12 < e1; e += 16) {
        int2 c0 = csr[e];
        int2 c1 = csr[e + 4];
        int2 c2 = csr[e + 8];
        int2 c3 = csr[e + 12];
        float4 v0 = ((const float4*)(h0 + (size_t)c0.x * NHID))[l];
        float4 v1 = ((const float4*)(h0 + (size_t)c1.x * NHID))[l];
        float4 v2 = ((const float4*)(h0 + (size_t)c2.x * NHID))[l];
        float4 v3 = ((const float4*)(h0 + (size_t)c3.x * NHID))[l];
        float w0 = __int_as_float(c0.y), w1 = __int_as_float(c1.y);
        float w2 = __int_as_float(c2.y), w3 = __int_as_float(c3.y);
        a0.x = fmaf(w0, v0.x, a0.x); a0.y = fmaf(w0, v0.y, a0.y);
        a0.z = fmaf(w0, v0.z, a0.z); a0.w = fmaf(w0, v0.w, a0.w);
        a1.x = fmaf(w1, v1.x, a1.x); a1.y = fmaf(w1, v1.y, a1.y);
        a1.z = fmaf(w1, v1.z, a1.z); a1.w = fmaf(w1, v1.w, a1.w);
        a2.x = fmaf(w2, v2.x, a2.x); a2.y = fmaf(w2, v2.y, a2.y);
        a2.z = fmaf(w2, v2.z, a2.z); a2.w = fmaf(w2, v2.w, a2.w);
        a3.x = fmaf(w3, v3.x, a3.x); a3.y = fmaf(w3, v3.y, a3.y);
        a3.z = fmaf(w3, v3.z, a3.z); a3.w = fmaf(w3, v3.w, a3.w);
    }
    for (; e < e1; e += 4) {
        int2 c0 = csr[e];
        float4 v0 = ((const float4*)(h0 + (size_t)c0.x * NHID))[l];
        float w0 = __int_as_float(c0.y);
        a0.x = fmaf(w0, v0.x, a0.x); a0.y = fmaf(w0, v0.y, a0.y);
        a0.z = fmaf(w0, v0.z, a0.z); a0.w = fmaf(w0, v0.w, a0.w);
    }
    a0.x += a1.x + a2.x + a3.x;
    a0.y += a1.y + a2.y + a3.y;
    a0.z += a1.z + a2.z + a3.z;
    a0.w += a1.w + a2.w + a3.w;
#pragma unroll
    for (int off = 16; off < 64; off <<= 1) {
        a0.x += __shfl_xor(a0.x, off, 64);
        a0.y += __shfl_xor(a0.y, off, 64);
        a0.z += __shfl_xor(a0.z, off, 64);
        a0.w += __shfl_xor(a0.w, off, 64);
    }
    if (lane < 16) {
        float di = dinv[n];
        float4 sv = ((const float4*)(h0 + (size_t)n * NHID))[l];
        float4 bv = ((const float4*)b1)[l];
        float4 r;
        r.x = fmaxf(fmaf(di, a0.x + sv.x, bv.x), 0.f);
        r.y = fmaxf(fmaf(di, a0.y + sv.y, bv.y), 0.f);
        r.z = fmaxf(fmaf(di, a0.z + sv.z, bv.z), 0.f);
        r.w = fmaxf(fmaf(di, a0.w + sv.w, bv.w), 0.f);
        ((float4*)(h + (size_t)n * NHID))[l] = r;
    }
}

// ---- GEMM2 + dinv scale: h2' = dinv[r] * (h @ W2) ----------------------
__global__ __launch_bounds__(256) void k_gemm2(const float* __restrict__ h,
                                               const float* __restrict__ W2,
                                               const float* __restrict__ dinv,
                                               float* __restrict__ h2, int N) {
    __shared__ float w[NHID * NCLS];    // 8 KB
    int t = threadIdx.x;
    const float4* W4 = (const float4*)W2;
    float4* w4 = (float4*)w;
    w4[t] = W4[t];
    if (t < 256) w4[t + 256] = W4[t + 256];
    __syncthreads();
    int wave = t >> 6, lane = t & 63;
    int rsub = lane >> 5, j = lane & 31;
    int r0 = blockIdx.x * 64 + wave * 16 + rsub;
    for (int i = 0; i < 8; i++) {
        int r = r0 + i * 2;
        if (r >= N) continue;
        const float4* hr = (const float4*)(h + (size_t)r * 64);
        float acc = 0.f;
#pragma unroll
        for (int k4 = 0; k4 < 16; k4++) {
            float4 hv = hr[k4];
            int k = k4 * 4;
            acc = fmaf(hv.x, w[(k + 0) * 32 + j], acc);
            acc = fmaf(hv.y, w[(k + 1) * 32 + j], acc);
            acc = fmaf(hv.z, w[(k + 2) * 32 + j], acc);
            acc = fmaf(hv.w, w[(k + 3) * 32 + j], acc);
        }
        h2[(size_t)r * 32 + j] = acc * dinv[r];
    }
}

// ---- agg2: out = di*(Agg + self) + b2, unroll x4 -----------------------
__global__ __launch_bounds__(256) void k_agg2(const float* __restrict__ h2,
                                              const int* __restrict__ rowptr,
                                              const int2* __restrict__ csr,
                                              const float* __restrict__ dinv,
                                              const float* __restrict__ b2,
                                              float* __restrict__ out, int N) {
    int t = threadIdx.x;
    int lane = t & 63;
    int n = blockIdx.x * 4 + (t >> 6);
    if (n >= N) return;
    int g = lane >> 3;
    int l = lane & 7;
    int e0 = rowptr[n], e1 = rowptr[n + 1];
    float4 a0 = make_float4(0.f, 0.f, 0.f, 0.f);
    float4 a1 = make_float4(0.f, 0.f, 0.f, 0.f);
    float4 a2 = make_float4(0.f, 0.f, 0.f, 0.f);
    float4 a3 = make_float4(0.f, 0.f, 0.f, 0.f);
    int e = e0 + g;
    for (; e + 24 < e1; e += 32) {
        int2 c0 = csr[e];
        int2 c1 = csr[e + 8];
        int2 c2 = csr[e + 16];
        int2 c3 = csr[e + 24];
        float4 v0 = ((const float4*)(h2 + (size_t)c0.x * NCLS))[l];
        float4 v1 = ((const float4*)(h2 + (size_t)c1.x * NCLS))[l];
        float4 v2 = ((const float4*)(h2 + (size_t)c2.x * NCLS))[l];
        float4 v3 = ((const float4*)(h2 + (size_t)c3.x * NCLS))[l];
        float w0 = __int_as_float(c0.y), w1 = __int_as_float(c1.y);
        float w2 = __int_as_float(c2.y), w3 = __int_as_float(c3.y);
        a0.x = fmaf(w0, v0.x, a0.x); a0.y = fmaf(w0, v0.y, a0.y);
        a0.z = fmaf(w0, v0.z, a0.z); a0.w = fmaf(w0, v0.w, a0.w);
        a1.x = fmaf(w1, v1.x, a1.x); a1.y = fmaf(w1, v1.y, a1.y);
        a1.z = fmaf(w1, v1.z, a1.z); a1.w = fmaf(w1, v1.w, a1.w);
        a2.x = fmaf(w2, v2.x, a2.x); a2.y = fmaf(w2, v2.y, a2.y);
        a2.z = fmaf(w2, v2.z, a2.z); a2.w = fmaf(w2, v2.w, a2.w);
        a3.x = fmaf(w3, v3.x, a3.x); a3.y = fmaf(w3, v3.y, a3.y);
        a3.z = fmaf(w3, v3.z, a3.z); a3.w = fmaf(w3, v3.w, a3.w);
    }
    for (; e < e1; e += 8) {
        int2 c0 = csr[e];
        float4 v0 = ((const float4*)(h2 + (size_t)c0.x * NCLS))[l];
        float w0 = __int_as_float(c0.y);
        a0.x = fmaf(w0, v0.x, a0.x); a0.y = fmaf(w0, v0.y, a0.y);
        a0.z = fmaf(w0, v0.z, a0.z); a0.w = fmaf(w0, v0.w, a0.w);
    }
    a0.x += a1.x + a2.x + a3.x;
    a0.y += a1.y + a2.y + a3.y;
    a0.z += a1.z + a2.z + a3.z;
    a0.w += a1.w + a2.w + a3.w;
#pragma unroll
    for (int off = 8; off < 64; off <<= 1) {
        a0.x += __shfl_xor(a0.x, off, 64);
        a0.y += __shfl_xor(a0.y, off, 64);
        a0.z += __shfl_xor(a0.z, off, 64);
        a0.w += __shfl_xor(a0.w, off, 64);
    }
    if (lane < 8) {
        float di = dinv[n];
        float4 sv = ((const float4*)(h2 + (size_t)n * NCLS))[l];
        float4 bv = ((const float4*)b2)[l];
        float4 r;
        r.x = fmaf(di, a0.x + sv.x, bv.x);
        r.y = fmaf(di, a0.y + sv.y, bv.y);
        r.z = fmaf(di, a0.z + sv.z, bv.z);
        r.w = fmaf(di, a0.w + sv.w, bv.w);
        ((float4*)(out + (size_t)n * NCLS))[l] = r;
    }
}

extern "C" void kernel_launch(void* const* d_in, const int* in_sizes, int n_in,
                              void* d_out, int out_size, void* d_ws, size_t ws_size,
                              hipStream_t stream) {
    const float* x   = (const float*)d_in[0];
    const int*   ei  = (const int*)d_in[1];     // [2, E] int32
    const float* A0  = (const float*)d_in[2];
    const float* A1  = (const float*)d_in[3];
    const float* wsv = (const float*)d_in[4];
    const float* W1  = (const float*)d_in[5];
    const float* b1  = (const float*)d_in[6];
    const float* W2  = (const float*)d_in[7];
    const float* b2  = (const float*)d_in[8];
    float* out = (float*)d_out;

    int N = in_sizes[0] / NFEAT;    // 100000
    int E = in_sizes[1] / 2;        // 3200000
    const int* rowv = ei;           // source
    const int* colv = ei + E;       // target

    char* p = (char*)d_ws;
    auto alloc = [&](size_t bytes) -> void* {
        void* q = (void*)p; p += (bytes + 255) & ~(size_t)255; return q;
    };
    float* dinv    = (float*)alloc((size_t)N * 4);
    int*   colsum  = (int*)  alloc((size_t)N * 4);
    int*   rowptr  = (int*)  alloc((size_t)(N + 1) * 4);
    int*   bsum    = (int*)  alloc(1024 * 4);
    int*   rank    = (int*)  alloc((size_t)E * 4);
    int2*  csr     = (int2*) alloc((size_t)E * 8);
    int*   hist    = (int*)  alloc((size_t)NC * N * 4);     // 25.6 MB
    float* h0      = (float*)alloc((size_t)N * NHID * 4);
    float* h       = (float*)alloc((size_t)N * NHID * 4);
    float* h2      = h0;            // reuse: h0 dead after agg1

    int NB  = (N + 1023) / 1024;    // 98 (<=128 required by k_scan2)
    int NR  = (N + RNG - 1) / RNG;  // 7 node ranges
    int epc = (E + NC - 1) / NC;    // 50000 edges per chunk

    k_hist<<<dim3(NC, NR), 256, 0, stream>>>(colv, rank, hist, N, E, epc);
    k_scan1<<<NB, 256, 0, stream>>>(hist, colsum, bsum, N);
    k_scan2<<<1, 128, 0, stream>>>(bsum, NB);
    k_scan3<<<NB, 256, 0, stream>>>(colsum, bsum, rowptr, hist, N, E);
    k_fill<<<(E + 255) / 256, 256, 0, stream>>>(rowv, colv, A0, A1, wsv, rank,
                                                hist, csr, N, E, epc);
    k_deg<<<(N + 3) / 4, 256, 0, stream>>>(csr, rowptr, dinv, N);
    k_gemm1<<<(N + 31) / 32, 256, 0, stream>>>(x, W1, dinv, h0, N);
    k_agg1<<<(N + 3) / 4, 256, 0, stream>>>(h0, rowptr, csr, dinv, b1, h, N);
    k_gemm2<<<(N + 63) / 64, 256, 0, stream>>>(h, W2, dinv, h2, N);
    k_agg2<<<(N + 3) / 4, 256, 0, stream>>>(h2, rowptr, csr, dinv, b2, out, N);
}

// Round 7
// 500.906 us; speedup vs baseline: 1.6916x; 1.4233x over previous
//
#include <hip/hip_runtime.h>

#define NFEAT 128
#define NHID  64
#define NCLS  32

#define RSH   7                 // 128 nodes per bucket
#define RNGB  128
#define NBKT  782               // ceil(100000 / 128)
#define BCAP  5120              // bucket capacity (mean 4092, sigma ~64)
#define EPB   16384             // edges per k_bin block

// ---- zero the global bucket counters (ws is poisoned every launch) -----
__global__ void k_zero(int* bktcnt) {
    int i = blockIdx.x * blockDim.x + threadIdx.x;
    if (i < NBKT) bktcnt[i] = 0;
}

// ---- phase 1: coarse binning by col>>7 ---------------------------------
// LDS histogram over 782 buckets; ONE returning global atomic per
// (block,bucket); scatter (packed, ew) into per-bucket regions (writes
// land in 782 hot L2 regions -> full-line eviction).
__global__ __launch_bounds__(256) void k_bin(const int* __restrict__ rowv,
                                             const int* __restrict__ colv,
                                             const float* __restrict__ A0,
                                             const float* __restrict__ A1,
                                             const float* __restrict__ wsv,
                                             int* bktcnt, int2* __restrict__ bin,
                                             int E) {
    __shared__ int hist[NBKT];
    __shared__ int cur[NBKT];
    int t = threadIdx.x;
    for (int i = t; i < NBKT; i += 256) hist[i] = 0;
    __syncthreads();
    int e0 = blockIdx.x * EPB, e1 = min(E, e0 + EPB);
    for (int e = e0 + t; e < e1; e += 256)
        atomicAdd(&hist[colv[e] >> RSH], 1);
    __syncthreads();
    for (int i = t; i < NBKT; i += 256) {
        int c = hist[i];
        cur[i] = (c > 0) ? atomicAdd(&bktcnt[i], c) : 0;
    }
    __syncthreads();
    float w0 = wsv[0], w1 = wsv[1];
    for (int e = e0 + t; e < e1; e += 256) {
        int c = colv[e];
        int b = c >> RSH;
        float ew = fmaf(w0, A0[e], w1 * A1[e]);
        int p = atomicAdd(&cur[b], 1);          // LDS, returns global in-bucket pos
        int pk = ((c & (RNGB - 1)) << 17) | rowv[e];
        if (p < BCAP) bin[(size_t)b * BCAP + p] = make_int2(pk, __float_as_int(ew));
    }
}

// ---- exclusive scan of 782 bucket counts (single block) ----------------
__global__ void k_bscan(const int* __restrict__ bktcnt, int* __restrict__ boff) {
    __shared__ int s[1024];
    int t = threadIdx.x;
    int v = (t < NBKT) ? bktcnt[t] : 0;
    s[t] = v; __syncthreads();
    for (int off = 1; off < 1024; off <<= 1) {
        int y = (t >= off) ? s[t - off] : 0;
        __syncthreads();
        s[t] += y;
        __syncthreads();
    }
    if (t < NBKT) boff[t] = s[t] - v;
    if (t == 1023) boff[NBKT] = s[1023];
}

// ---- phase 2: per-bucket exact CSR + rowptr + dinv (LDS atomics only) --
__global__ __launch_bounds__(256) void k_build(const int2* __restrict__ bin,
                                               const int* __restrict__ bktcnt,
                                               const int* __restrict__ boff,
                                               int* __restrict__ rowptr,
                                               float* __restrict__ dinv,
                                               int2* __restrict__ csr,
                                               int N, int E) {
    __shared__ int   hist[RNGB];
    __shared__ int   cur[RNGB];
    __shared__ float fdeg[RNGB];
    __shared__ int   sc[RNGB];
    int b = blockIdx.x, t = threadIdx.x;
    int cnt = min(bktcnt[b], BCAP);
    int base = boff[b];
    if (t < RNGB) { hist[t] = 0; fdeg[t] = 0.f; }
    __syncthreads();
    const int2* mb = bin + (size_t)b * BCAP;
    for (int i = t; i < cnt; i += 256) {
        int2 v = mb[i];
        int co = v.x >> 17;
        atomicAdd(&hist[co], 1);
        atomicAdd(&fdeg[co], __int_as_float(v.y));
    }
    __syncthreads();
    if (t < RNGB) sc[t] = hist[t];
    __syncthreads();
    for (int off = 1; off < RNGB; off <<= 1) {
        int y = (t < RNGB && t >= off) ? sc[t - off] : 0;
        __syncthreads();
        if (t < RNGB) sc[t] += y;
        __syncthreads();
    }
    int node0 = b << RSH;
    if (t < RNGB) {
        int ex = sc[t] - hist[t];               // exclusive prefix
        cur[t] = ex;
        int node = node0 + t;
        if (node < N) {
            rowptr[node] = base + ex;
            dinv[node] = rsqrtf(1.0f + fdeg[t]);
        }
    }
    if (b == NBKT - 1 && t == 0) rowptr[N] = E;
    __syncthreads();
    for (int i = t; i < cnt; i += 256) {
        int2 v = mb[i];
        int co = v.x >> 17;
        int r = v.x & 0x1FFFF;
        int p = atomicAdd(&cur[co], 1);         // LDS rank
        csr[base + p] = make_int2(r, v.y);
    }
}

// ---- GEMM1 (register-tiled) + dinv scale: h0' = dinv[r]*(x @ W1) -------
// 64-row tile, thread = 4 rows x 4 cols. xs row-major padded, ws k-major.
__global__ __launch_bounds__(256) void k_gemm1(const float* __restrict__ x,
                                               const float* __restrict__ W1,
                                               const float* __restrict__ dinv,
                                               float* __restrict__ h0, int N) {
    __shared__ float xs[64 * 132];      // 64 rows x (128 + 4 pad)
    __shared__ float ws[128 * 64];
    int t = threadIdx.x;
    int r0 = blockIdx.x * 64;
    {
        const float4* W4 = (const float4*)W1;
        float4* w4 = (float4*)ws;
#pragma unroll
        for (int i = 0; i < 8; i++) w4[t + 256 * i] = W4[t + 256 * i];
    }
#pragma unroll
    for (int m = 0; m < 8; m++) {
        int idx = t + 256 * m;          // 0..2047
        int row = idx >> 5, k4 = idx & 31;
        int g = r0 + row;
        float4 v = make_float4(0.f, 0.f, 0.f, 0.f);
        if (g < N) v = ((const float4*)x)[(size_t)g * 32 + k4];
        *(float4*)&xs[row * 132 + k4 * 4] = v;
    }
    __syncthreads();
    int i = t >> 4, j = t & 15;
    float acc[4][4] = {};
    const float* xr = &xs[(4 * i) * 132];
    const float* wc = &ws[4 * j];
#pragma unroll 4
    for (int k = 0; k < 128; k++) {
        float a0 = xr[k], a1 = xr[132 + k], a2 = xr[264 + k], a3 = xr[396 + k];
        float4 w = *(const float4*)&wc[k * 64];
        acc[0][0] = fmaf(a0, w.x, acc[0][0]);
        acc[0][1] = fmaf(a0, w.y, acc[0][1]);
        acc[0][2] = fmaf(a0, w.z, acc[0][2]);
        acc[0][3] = fmaf(a0, w.w, acc[0][3]);
        acc[1][0] = fmaf(a1, w.x, acc[1][0]);
        acc[1][1] = fmaf(a1, w.y, acc[1][1]);
        acc[1][2] = fmaf(a1, w.z, acc[1][2]);
        acc[1][3] = fmaf(a1, w.w, acc[1][3]);
        acc[2][0] = fmaf(a2, w.x, acc[2][0]);
        acc[2][1] = fmaf(a2, w.y, acc[2][1]);
        acc[2][2] = fmaf(a2, w.z, acc[2][2]);
        acc[2][3] = fmaf(a2, w.w, acc[2][3]);
        acc[3][0] = fmaf(a3, w.x, acc[3][0]);
        acc[3][1] = fmaf(a3, w.y, acc[3][1]);
        acc[3][2] = fmaf(a3, w.z, acc[3][2]);
        acc[3][3] = fmaf(a3, w.w, acc[3][3]);
    }
#pragma unroll
    for (int r = 0; r < 4; r++) {
        int g = r0 + 4 * i + r;
        if (g < N) {
            float d = dinv[g];
            ((float4*)h0)[(size_t)g * 16 + j] =
                make_float4(acc[r][0] * d, acc[r][1] * d, acc[r][2] * d, acc[r][3] * d);
        }
    }
}

// ---- agg1 + relu: h = relu(di*(Agg + self) + b1), unroll x4 ------------
__global__ __launch_bounds__(256) void k_agg1(const float* __restrict__ h0,
                                              const int* __restrict__ rowptr,
                                              const int2* __restrict__ csr,
                                              const float* __restrict__ dinv,
                                              const float* __restrict__ b1,
                                              float* __restrict__ h, int N) {
    int t = threadIdx.x;
    int lane = t & 63;
    int n = blockIdx.x * 4 + (t >> 6);
    if (n >= N) return;
    int g = lane >> 4;
    int l = lane & 15;
    int e0 = rowptr[n], e1 = rowptr[n + 1];
    float4 a0 = make_float4(0.f, 0.f, 0.f, 0.f);
    float4 a1 = make_float4(0.f, 0.f, 0.f, 0.f);
    float4 a2 = make_float4(0.f, 0.f, 0.f, 0.f);
    float4 a3 = make_float4(0.f, 0.f, 0.f, 0.f);
    int e = e0 + g;
    for (; e + 12 < e1; e += 16) {
        int2 c0 = csr[e];
        int2 c1 = csr[e + 4];
        int2 c2 = csr[e + 8];
        int2 c3 = csr[e + 12];
        float4 v0 = ((const float4*)(h0 + (size_t)c0.x * NHID))[l];
        float4 v1 = ((const float4*)(h0 + (size_t)c1.x * NHID))[l];
        float4 v2 = ((const float4*)(h0 + (size_t)c2.x * NHID))[l];
        float4 v3 = ((const float4*)(h0 + (size_t)c3.x * NHID))[l];
        float w0 = __int_as_float(c0.y), w1 = __int_as_float(c1.y);
        float w2 = __int_as_float(c2.y), w3 = __int_as_float(c3.y);
        a0.x = fmaf(w0, v0.x, a0.x); a0.y = fmaf(w0, v0.y, a0.y);
        a0.z = fmaf(w0, v0.z, a0.z); a0.w = fmaf(w0, v0.w, a0.w);
        a1.x = fmaf(w1, v1.x, a1.x); a1.y = fmaf(w1, v1.y, a1.y);
        a1.z = fmaf(w1, v1.z, a1.z); a1.w = fmaf(w1, v1.w, a1.w);
        a2.x = fmaf(w2, v2.x, a2.x); a2.y = fmaf(w2, v2.y, a2.y);
        a2.z = fmaf(w2, v2.z, a2.z); a2.w = fmaf(w2, v2.w, a2.w);
        a3.x = fmaf(w3, v3.x, a3.x); a3.y = fmaf(w3, v3.y, a3.y);
        a3.z = fmaf(w3, v3.z, a3.z); a3.w = fmaf(w3, v3.w, a3.w);
    }
    for (; e < e1; e += 4) {
        int2 c0 = csr[e];
        float4 v0 = ((const float4*)(h0 + (size_t)c0.x * NHID))[l];
        float w0 = __int_as_float(c0.y);
        a0.x = fmaf(w0, v0.x, a0.x); a0.y = fmaf(w0, v0.y, a0.y);
        a0.z = fmaf(w0, v0.z, a0.z); a0.w = fmaf(w0, v0.w, a0.w);
    }
    a0.x += a1.x + a2.x + a3.x;
    a0.y += a1.y + a2.y + a3.y;
    a0.z += a1.z + a2.z + a3.z;
    a0.w += a1.w + a2.w + a3.w;
#pragma unroll
    for (int off = 16; off < 64; off <<= 1) {
        a0.x += __shfl_xor(a0.x, off, 64);
        a0.y += __shfl_xor(a0.y, off, 64);
        a0.z += __shfl_xor(a0.z, off, 64);
        a0.w += __shfl_xor(a0.w, off, 64);
    }
    if (lane < 16) {
        float di = dinv[n];
        float4 sv = ((const float4*)(h0 + (size_t)n * NHID))[l];
        float4 bv = ((const float4*)b1)[l];
        float4 r;
        r.x = fmaxf(fmaf(di, a0.x + sv.x, bv.x), 0.f);
        r.y = fmaxf(fmaf(di, a0.y + sv.y, bv.y), 0.f);
        r.z = fmaxf(fmaf(di, a0.z + sv.z, bv.z), 0.f);
        r.w = fmaxf(fmaf(di, a0.w + sv.w, bv.w), 0.f);
        ((float4*)(h + (size_t)n * NHID))[l] = r;
    }
}

// ---- GEMM2 (register-tiled) + dinv scale: h2' = dinv[r]*(h @ W2) -------
// 64-row tile, 128 threads, thread = 4 rows x 4 cols.
__global__ __launch_bounds__(128) void k_gemm2(const float* __restrict__ h,
                                               const float* __restrict__ W2,
                                               const float* __restrict__ dinv,
                                               float* __restrict__ h2, int N) {
    __shared__ float hs[64 * 68];   // 64 rows x (64 + 4 pad)
    __shared__ float ws[64 * 32];
    int t = threadIdx.x;
    int r0 = blockIdx.x * 64;
    {
        const float4* W4 = (const float4*)W2;
        float4* w4 = (float4*)ws;
#pragma unroll
        for (int i = 0; i < 4; i++) w4[t + 128 * i] = W4[t + 128 * i];
    }
#pragma unroll
    for (int m = 0; m < 8; m++) {
        int idx = t + 128 * m;          // 0..1023
        int row = idx >> 4, k4 = idx & 15;
        int g = r0 + row;
        float4 v = make_float4(0.f, 0.f, 0.f, 0.f);
        if (g < N) v = ((const float4*)h)[(size_t)g * 16 + k4];
        *(float4*)&hs[row * 68 + k4 * 4] = v;
    }
    __syncthreads();
    int i = t >> 3, j = t & 7;
    float acc[4][4] = {};
    const float* hr = &hs[(4 * i) * 68];
    const float* wc = &ws[4 * j];
#pragma unroll 4
    for (int k = 0; k < 64; k++) {
        float a0 = hr[k], a1 = hr[68 + k], a2 = hr[136 + k], a3 = hr[204 + k];
        float4 w = *(const float4*)&wc[k * 32];
        acc[0][0] = fmaf(a0, w.x, acc[0][0]);
        acc[0][1] = fmaf(a0, w.y, acc[0][1]);
        acc[0][2] = fmaf(a0, w.z, acc[0][2]);
        acc[0][3] = fmaf(a0, w.w, acc[0][3]);
        acc[1][0] = fmaf(a1, w.x, acc[1][0]);
        acc[1][1] = fmaf(a1, w.y, acc[1][1]);
        acc[1][2] = fmaf(a1, w.z, acc[1][2]);
        acc[1][3] = fmaf(a1, w.w, acc[1][3]);
        acc[2][0] = fmaf(a2, w.x, acc[2][0]);
        acc[2][1] = fmaf(a2, w.y, acc[2][1]);
        acc[2][2] = fmaf(a2, w.z, acc[2][2]);
        acc[2][3] = fmaf(a2, w.w, acc[2][3]);
        acc[3][0] = fmaf(a3, w.x, acc[3][0]);
        acc[3][1] = fmaf(a3, w.y, acc[3][1]);
        acc[3][2] = fmaf(a3, w.z, acc[3][2]);
        acc[3][3] = fmaf(a3, w.w, acc[3][3]);
    }
#pragma unroll
    for (int r = 0; r < 4; r++) {
        int g = r0 + 4 * i + r;
        if (g < N) {
            float d = dinv[g];
            ((float4*)h2)[(size_t)g * 8 + j] =
                make_float4(acc[r][0] * d, acc[r][1] * d, acc[r][2] * d, acc[r][3] * d);
        }
    }
}

// ---- agg2: out = di*(Agg + self) + b2, unroll x4 -----------------------
__global__ __launch_bounds__(256) void k_agg2(const float* __restrict__ h2,
                                              const int* __restrict__ rowptr,
                                              const int2* __restrict__ csr,
                                              const float* __restrict__ dinv,
                                              const float* __restrict__ b2,
                                              float* __restrict__ out, int N) {
    int t = threadIdx.x;
    int lane = t & 63;
    int n = blockIdx.x * 4 + (t >> 6);
    if (n >= N) return;
    int g = lane >> 3;
    int l = lane & 7;
    int e0 = rowptr[n], e1 = rowptr[n + 1];
    float4 a0 = make_float4(0.f, 0.f, 0.f, 0.f);
    float4 a1 = make_float4(0.f, 0.f, 0.f, 0.f);
    float4 a2 = make_float4(0.f, 0.f, 0.f, 0.f);
    float4 a3 = make_float4(0.f, 0.f, 0.f, 0.f);
    int e = e0 + g;
    for (; e + 24 < e1; e += 32) {
        int2 c0 = csr[e];
        int2 c1 = csr[e + 8];
        int2 c2 = csr[e + 16];
        int2 c3 = csr[e + 24];
        float4 v0 = ((const float4*)(h2 + (size_t)c0.x * NCLS))[l];
        float4 v1 = ((const float4*)(h2 + (size_t)c1.x * NCLS))[l];
        float4 v2 = ((const float4*)(h2 + (size_t)c2.x * NCLS))[l];
        float4 v3 = ((const float4*)(h2 + (size_t)c3.x * NCLS))[l];
        float w0 = __int_as_float(c0.y), w1 = __int_as_float(c1.y);
        float w2 = __int_as_float(c2.y), w3 = __int_as_float(c3.y);
        a0.x = fmaf(w0, v0.x, a0.x); a0.y = fmaf(w0, v0.y, a0.y);
        a0.z = fmaf(w0, v0.z, a0.z); a0.w = fmaf(w0, v0.w, a0.w);
        a1.x = fmaf(w1, v1.x, a1.x); a1.y = fmaf(w1, v1.y, a1.y);
        a1.z = fmaf(w1, v1.z, a1.z); a1.w = fmaf(w1, v1.w, a1.w);
        a2.x = fmaf(w2, v2.x, a2.x); a2.y = fmaf(w2, v2.y, a2.y);
        a2.z = fmaf(w2, v2.z, a2.z); a2.w = fmaf(w2, v2.w, a2.w);
        a3.x = fmaf(w3, v3.x, a3.x); a3.y = fmaf(w3, v3.y, a3.y);
        a3.z = fmaf(w3, v3.z, a3.z); a3.w = fmaf(w3, v3.w, a3.w);
    }
    for (; e < e1; e += 8) {
        int2 c0 = csr[e];
        float4 v0 = ((const float4*)(h2 + (size_t)c0.x * NCLS))[l];
        float w0 = __int_as_float(c0.y);
        a0.x = fmaf(w0, v0.x, a0.x); a0.y = fmaf(w0, v0.y, a0.y);
        a0.z = fmaf(w0, v0.z, a0.z); a0.w = fmaf(w0, v0.w, a0.w);
    }
    a0.x += a1.x + a2.x + a3.x;
    a0.y += a1.y + a2.y + a3.y;
    a0.z += a1.z + a2.z + a3.z;
    a0.w += a1.w + a2.w + a3.w;
#pragma unroll
    for (int off = 8; off < 64; off <<= 1) {
        a0.x += __shfl_xor(a0.x, off, 64);
        a0.y += __shfl_xor(a0.y, off, 64);
        a0.z += __shfl_xor(a0.z, off, 64);
        a0.w += __shfl_xor(a0.w, off, 64);
    }
    if (lane < 8) {
        float di = dinv[n];
        float4 sv = ((const float4*)(h2 + (size_t)n * NCLS))[l];
        float4 bv = ((const float4*)b2)[l];
        float4 r;
        r.x = fmaf(di, a0.x + sv.x, bv.x);
        r.y = fmaf(di, a0.y + sv.y, bv.y);
        r.z = fmaf(di, a0.z + sv.z, bv.z);
        r.w = fmaf(di, a0.w + sv.w, bv.w);
        ((float4*)(out + (size_t)n * NCLS))[l] = r;
    }
}

extern "C" void kernel_launch(void* const* d_in, const int* in_sizes, int n_in,
                              void* d_out, int out_size, void* d_ws, size_t ws_size,
                              hipStream_t stream) {
    const float* x   = (const float*)d_in[0];
    const int*   ei  = (const int*)d_in[1];     // [2, E] int32
    const float* A0  = (const float*)d_in[2];
    const float* A1  = (const float*)d_in[3];
    const float* wsv = (const float*)d_in[4];
    const float* W1  = (const float*)d_in[5];
    const float* b1  = (const float*)d_in[6];
    const float* W2  = (const float*)d_in[7];
    const float* b2  = (const float*)d_in[8];
    float* out = (float*)d_out;

    int N = in_sizes[0] / NFEAT;    // 100000
    int E = in_sizes[1] / 2;        // 3200000
    const int* rowv = ei;           // source
    const int* colv = ei + E;       // target

    char* p = (char*)d_ws;
    auto alloc = [&](size_t bytes) -> void* {
        void* q = (void*)p; p += (bytes + 255) & ~(size_t)255; return q;
    };
    float* dinv    = (float*)alloc((size_t)N * 4);
    int*   rowptr  = (int*)  alloc((size_t)(N + 1) * 4);
    int*   bktcnt  = (int*)  alloc((size_t)NBKT * 4);
    int*   boff    = (int*)  alloc((size_t)(NBKT + 1) * 4);
    int2*  bin     = (int2*) alloc((size_t)NBKT * BCAP * 8);   // 32 MB
    int2*  csr     = (int2*) alloc((size_t)E * 8);             // 25.6 MB
    float* h0      = (float*)alloc((size_t)N * NHID * 4);      // 25.6 MB
    float* h       = (float*)alloc((size_t)N * NHID * 4);      // 25.6 MB
    float* h2      = h0;            // reuse: h0 dead after agg1

    k_zero<<<(NBKT + 255) / 256, 256, 0, stream>>>(bktcnt);
    k_bin<<<(E + EPB - 1) / EPB, 256, 0, stream>>>(rowv, colv, A0, A1, wsv,
                                                   bktcnt, bin, E);
    k_bscan<<<1, 1024, 0, stream>>>(bktcnt, boff);
    k_build<<<NBKT, 256, 0, stream>>>(bin, bktcnt, boff, rowptr, dinv, csr, N, E);
    k_gemm1<<<(N + 63) / 64, 256, 0, stream>>>(x, W1, dinv, h0, N);
    k_agg1<<<(N + 3) / 4, 256, 0, stream>>>(h0, rowptr, csr, dinv, b1, h, N);
    k_gemm2<<<(N + 63) / 64, 128, 0, stream>>>(h, W2, dinv, h2, N);
    k_agg2<<<(N + 3) / 4, 256, 0, stream>>>(h2, rowptr, csr, dinv, b2, out, N);
}

// Round 8
// 492.499 us; speedup vs baseline: 1.7205x; 1.0171x over previous
//
#include <hip/hip_runtime.h>

#define NFEAT 128
#define NHID  64
#define NCLS  32

#define RSH   7                 // 128 nodes per bucket
#define RNGB  128
#define NBKT  782               // ceil(100000 / 128)
#define EPB   4096              // edges per binning block
#define NBLK  782               // ceil(3200000 / 4096)

// ---- pass 1: per-block LDS histogram over 782 buckets ------------------
__global__ __launch_bounds__(256) void k_count(const int* __restrict__ colv,
                                               int* __restrict__ hist, int E) {
    __shared__ int lh[NBKT];
    int t = threadIdx.x, blk = blockIdx.x;
    for (int i = t; i < NBKT; i += 256) lh[i] = 0;
    __syncthreads();
    int e0 = blk * EPB, e1 = min(E, e0 + EPB);
    for (int e = e0 + t; e < e1; e += 256)
        atomicAdd(&lh[colv[e] >> RSH], 1);
    __syncthreads();
    int* row = hist + (size_t)blk * NBKT;
    for (int i = t; i < NBKT; i += 256) row[i] = lh[i];
}

// ---- pass 2: per-bucket exclusive scan over blocks (in place) ----------
// block b: hist[blk][b] -> sum_{blk'<blk} hist[blk'][b];  colsum[b] = total
__global__ __launch_bounds__(1024) void k_colsum(int* __restrict__ hist,
                                                 int* __restrict__ colsum) {
    __shared__ int s[1024];
    int t = threadIdx.x, b = blockIdx.x;
    int v = (t < NBLK) ? hist[(size_t)t * NBKT + b] : 0;
    s[t] = v; __syncthreads();
    for (int off = 1; off < 1024; off <<= 1) {
        int y = (t >= off) ? s[t - off] : 0;
        __syncthreads();
        s[t] += y;
        __syncthreads();
    }
    if (t < NBLK) hist[(size_t)t * NBKT + b] = s[t] - v;    // exclusive
    if (t == NBLK - 1) colsum[b] = s[t];
}

// ---- pass 3: exclusive scan of 782 bucket totals -> boff ---------------
__global__ void k_bscan(const int* __restrict__ colsum, int* __restrict__ boff) {
    __shared__ int s[1024];
    int t = threadIdx.x;
    int v = (t < NBKT) ? colsum[t] : 0;
    s[t] = v; __syncthreads();
    for (int off = 1; off < 1024; off <<= 1) {
        int y = (t >= off) ? s[t - off] : 0;
        __syncthreads();
        s[t] += y;
        __syncthreads();
    }
    if (t < NBKT) boff[t] = s[t] - v;
    if (t == 1023) boff[NBKT] = s[1023];
}

// ---- pass 4: scatter into exact bucket-sorted positions (LDS ranks) ----
__global__ __launch_bounds__(256) void k_scatter(const int* __restrict__ rowv,
                                                 const int* __restrict__ colv,
                                                 const float* __restrict__ A0,
                                                 const float* __restrict__ A1,
                                                 const float* __restrict__ wsv,
                                                 const int* __restrict__ hist,
                                                 const int* __restrict__ boff,
                                                 int2* __restrict__ bin, int E) {
    __shared__ int cur[NBKT];
    int t = threadIdx.x, blk = blockIdx.x;
    const int* row = hist + (size_t)blk * NBKT;
    for (int i = t; i < NBKT; i += 256) cur[i] = boff[i] + row[i];
    __syncthreads();
    int e0 = blk * EPB, e1 = min(E, e0 + EPB);
    float w0 = wsv[0], w1 = wsv[1];
    for (int e = e0 + t; e < e1; e += 256) {
        int c = colv[e];
        int b = c >> RSH;
        float ew = fmaf(w0, A0[e], w1 * A1[e]);
        int p = atomicAdd(&cur[b], 1);          // LDS returning
        int pk = ((c & (RNGB - 1)) << 17) | rowv[e];
        bin[p] = make_int2(pk, __float_as_int(ew));
    }
}

// ---- pass 5: per-bucket exact CSR + rowptr + dinv (LDS atomics only) ---
__global__ __launch_bounds__(256) void k_build(const int2* __restrict__ bin,
                                               const int* __restrict__ boff,
                                               int* __restrict__ rowptr,
                                               float* __restrict__ dinv,
                                               int2* __restrict__ csr,
                                               int N, int E) {
    __shared__ int   hist[RNGB];
    __shared__ int   cur[RNGB];
    __shared__ float fdeg[RNGB];
    __shared__ int   sc[RNGB];
    int b = blockIdx.x, t = threadIdx.x;
    int base = boff[b];
    int cnt = boff[b + 1] - base;
    if (t < RNGB) { hist[t] = 0; fdeg[t] = 0.f; }
    __syncthreads();
    const int2* mb = bin + base;
    for (int i = t; i < cnt; i += 256) {
        int2 v = mb[i];
        int co = v.x >> 17;
        atomicAdd(&hist[co], 1);
        atomicAdd(&fdeg[co], __int_as_float(v.y));
    }
    __syncthreads();
    if (t < RNGB) sc[t] = hist[t];
    __syncthreads();
    for (int off = 1; off < RNGB; off <<= 1) {
        int y = (t < RNGB && t >= off) ? sc[t - off] : 0;
        __syncthreads();
        if (t < RNGB) sc[t] += y;
        __syncthreads();
    }
    int node0 = b << RSH;
    if (t < RNGB) {
        int ex = sc[t] - hist[t];               // exclusive prefix
        cur[t] = ex;
        int node = node0 + t;
        if (node < N) {
            rowptr[node] = base + ex;
            dinv[node] = rsqrtf(1.0f + fdeg[t]);
        }
    }
    if (b == NBKT - 1 && t == 0) rowptr[N] = E;
    __syncthreads();
    for (int i = t; i < cnt; i += 256) {
        int2 v = mb[i];
        int co = v.x >> 17;
        int r = v.x & 0x1FFFF;
        int p = atomicAdd(&cur[co], 1);         // LDS rank
        csr[base + p] = make_int2(r, v.y);
    }
}

// ---- GEMM1 (register-tiled) + dinv scale: h0' = dinv[r]*(x @ W1) -------
__global__ __launch_bounds__(256) void k_gemm1(const float* __restrict__ x,
                                               const float* __restrict__ W1,
                                               const float* __restrict__ dinv,
                                               float* __restrict__ h0, int N) {
    __shared__ float xs[64 * 132];      // 64 rows x (128 + 4 pad)
    __shared__ float ws[128 * 64];
    int t = threadIdx.x;
    int r0 = blockIdx.x * 64;
    {
        const float4* W4 = (const float4*)W1;
        float4* w4 = (float4*)ws;
#pragma unroll
        for (int i = 0; i < 8; i++) w4[t + 256 * i] = W4[t + 256 * i];
    }
#pragma unroll
    for (int m = 0; m < 8; m++) {
        int idx = t + 256 * m;          // 0..2047
        int row = idx >> 5, k4 = idx & 31;
        int g = r0 + row;
        float4 v = make_float4(0.f, 0.f, 0.f, 0.f);
        if (g < N) v = ((const float4*)x)[(size_t)g * 32 + k4];
        *(float4*)&xs[row * 132 + k4 * 4] = v;
    }
    __syncthreads();
    int i = t >> 4, j = t & 15;
    float acc[4][4] = {};
    const float* xr = &xs[(4 * i) * 132];
    const float* wc = &ws[4 * j];
#pragma unroll 4
    for (int k = 0; k < 128; k++) {
        float a0 = xr[k], a1 = xr[132 + k], a2 = xr[264 + k], a3 = xr[396 + k];
        float4 w = *(const float4*)&wc[k * 64];
        acc[0][0] = fmaf(a0, w.x, acc[0][0]);
        acc[0][1] = fmaf(a0, w.y, acc[0][1]);
        acc[0][2] = fmaf(a0, w.z, acc[0][2]);
        acc[0][3] = fmaf(a0, w.w, acc[0][3]);
        acc[1][0] = fmaf(a1, w.x, acc[1][0]);
        acc[1][1] = fmaf(a1, w.y, acc[1][1]);
        acc[1][2] = fmaf(a1, w.z, acc[1][2]);
        acc[1][3] = fmaf(a1, w.w, acc[1][3]);
        acc[2][0] = fmaf(a2, w.x, acc[2][0]);
        acc[2][1] = fmaf(a2, w.y, acc[2][1]);
        acc[2][2] = fmaf(a2, w.z, acc[2][2]);
        acc[2][3] = fmaf(a2, w.w, acc[2][3]);
        acc[3][0] = fmaf(a3, w.x, acc[3][0]);
        acc[3][1] = fmaf(a3, w.y, acc[3][1]);
        acc[3][2] = fmaf(a3, w.z, acc[3][2]);
        acc[3][3] = fmaf(a3, w.w, acc[3][3]);
    }
#pragma unroll
    for (int r = 0; r < 4; r++) {
        int g = r0 + 4 * i + r;
        if (g < N) {
            float d = dinv[g];
            ((float4*)h0)[(size_t)g * 16 + j] =
                make_float4(acc[r][0] * d, acc[r][1] * d, acc[r][2] * d, acc[r][3] * d);
        }
    }
}

// ---- agg1 + relu: h = relu(di*(Agg + self) + b1), unroll x4 ------------
__global__ __launch_bounds__(256) void k_agg1(const float* __restrict__ h0,
                                              const int* __restrict__ rowptr,
                                              const int2* __restrict__ csr,
                                              const float* __restrict__ dinv,
                                              const float* __restrict__ b1,
                                              float* __restrict__ h, int N) {
    int t = threadIdx.x;
    int lane = t & 63;
    int n = blockIdx.x * 4 + (t >> 6);
    if (n >= N) return;
    int g = lane >> 4;
    int l = lane & 15;
    int e0 = rowptr[n], e1 = rowptr[n + 1];
    float4 a0 = make_float4(0.f, 0.f, 0.f, 0.f);
    float4 a1 = make_float4(0.f, 0.f, 0.f, 0.f);
    float4 a2 = make_float4(0.f, 0.f, 0.f, 0.f);
    float4 a3 = make_float4(0.f, 0.f, 0.f, 0.f);
    int e = e0 + g;
    for (; e + 12 < e1; e += 16) {
        int2 c0 = csr[e];
        int2 c1 = csr[e + 4];
        int2 c2 = csr[e + 8];
        int2 c3 = csr[e + 12];
        float4 v0 = ((const float4*)(h0 + (size_t)c0.x * NHID))[l];
        float4 v1 = ((const float4*)(h0 + (size_t)c1.x * NHID))[l];
        float4 v2 = ((const float4*)(h0 + (size_t)c2.x * NHID))[l];
        float4 v3 = ((const float4*)(h0 + (size_t)c3.x * NHID))[l];
        float w0 = __int_as_float(c0.y), w1 = __int_as_float(c1.y);
        float w2 = __int_as_float(c2.y), w3 = __int_as_float(c3.y);
        a0.x = fmaf(w0, v0.x, a0.x); a0.y = fmaf(w0, v0.y, a0.y);
        a0.z = fmaf(w0, v0.z, a0.z); a0.w = fmaf(w0, v0.w, a0.w);
        a1.x = fmaf(w1, v1.x, a1.x); a1.y = fmaf(w1, v1.y, a1.y);
        a1.z = fmaf(w1, v1.z, a1.z); a1.w = fmaf(w1, v1.w, a1.w);
        a2.x = fmaf(w2, v2.x, a2.x); a2.y = fmaf(w2, v2.y, a2.y);
        a2.z = fmaf(w2, v2.z, a2.z); a2.w = fmaf(w2, v2.w, a2.w);
        a3.x = fmaf(w3, v3.x, a3.x); a3.y = fmaf(w3, v3.y, a3.y);
        a3.z = fmaf(w3, v3.z, a3.z); a3.w = fmaf(w3, v3.w, a3.w);
    }
    for (; e < e1; e += 4) {
        int2 c0 = csr[e];
        float4 v0 = ((const float4*)(h0 + (size_t)c0.x * NHID))[l];
        float w0 = __int_as_float(c0.y);
        a0.x = fmaf(w0, v0.x, a0.x); a0.y = fmaf(w0, v0.y, a0.y);
        a0.z = fmaf(w0, v0.z, a0.z); a0.w = fmaf(w0, v0.w, a0.w);
    }
    a0.x += a1.x + a2.x + a3.x;
    a0.y += a1.y + a2.y + a3.y;
    a0.z += a1.z + a2.z + a3.z;
    a0.w += a1.w + a2.w + a3.w;
#pragma unroll
    for (int off = 16; off < 64; off <<= 1) {
        a0.x += __shfl_xor(a0.x, off, 64);
        a0.y += __shfl_xor(a0.y, off, 64);
        a0.z += __shfl_xor(a0.z, off, 64);
        a0.w += __shfl_xor(a0.w, off, 64);
    }
    if (lane < 16) {
        float di = dinv[n];
        float4 sv = ((const float4*)(h0 + (size_t)n * NHID))[l];
        float4 bv = ((const float4*)b1)[l];
        float4 r;
        r.x = fmaxf(fmaf(di, a0.x + sv.x, bv.x), 0.f);
        r.y = fmaxf(fmaf(di, a0.y + sv.y, bv.y), 0.f);
        r.z = fmaxf(fmaf(di, a0.z + sv.z, bv.z), 0.f);
        r.w = fmaxf(fmaf(di, a0.w + sv.w, bv.w), 0.f);
        ((float4*)(h + (size_t)n * NHID))[l] = r;
    }
}

// ---- GEMM2 (register-tiled) + dinv scale: h2' = dinv[r]*(h @ W2) -------
__global__ __launch_bounds__(128) void k_gemm2(const float* __restrict__ h,
                                               const float* __restrict__ W2,
                                               const float* __restrict__ dinv,
                                               float* __restrict__ h2, int N) {
    __shared__ float hs[64 * 68];   // 64 rows x (64 + 4 pad)
    __shared__ float ws[64 * 32];
    int t = threadIdx.x;
    int r0 = blockIdx.x * 64;
    {
        const float4* W4 = (const float4*)W2;
        float4* w4 = (float4*)ws;
#pragma unroll
        for (int i = 0; i < 4; i++) w4[t + 128 * i] = W4[t + 128 * i];
    }
#pragma unroll
    for (int m = 0; m < 8; m++) {
        int idx = t + 128 * m;          // 0..1023
        int row = idx >> 4, k4 = idx & 15;
        int g = r0 + row;
        float4 v = make_float4(0.f, 0.f, 0.f, 0.f);
        if (g < N) v = ((const float4*)h)[(size_t)g * 16 + k4];
        *(float4*)&hs[row * 68 + k4 * 4] = v;
    }
    __syncthreads();
    int i = t >> 3, j = t & 7;
    float acc[4][4] = {};
    const float* hr = &hs[(4 * i) * 68];
    const float* wc = &ws[4 * j];
#pragma unroll 4
    for (int k = 0; k < 64; k++) {
        float a0 = hr[k], a1 = hr[68 + k], a2 = hr[136 + k], a3 = hr[204 + k];
        float4 w = *(const float4*)&wc[k * 32];
        acc[0][0] = fmaf(a0, w.x, acc[0][0]);
        acc[0][1] = fmaf(a0, w.y, acc[0][1]);
        acc[0][2] = fmaf(a0, w.z, acc[0][2]);
        acc[0][3] = fmaf(a0, w.w, acc[0][3]);
        acc[1][0] = fmaf(a1, w.x, acc[1][0]);
        acc[1][1] = fmaf(a1, w.y, acc[1][1]);
        acc[1][2] = fmaf(a1, w.z, acc[1][2]);
        acc[1][3] = fmaf(a1, w.w, acc[1][3]);
        acc[2][0] = fmaf(a2, w.x, acc[2][0]);
        acc[2][1] = fmaf(a2, w.y, acc[2][1]);
        acc[2][2] = fmaf(a2, w.z, acc[2][2]);
        acc[2][3] = fmaf(a2, w.w, acc[2][3]);
        acc[3][0] = fmaf(a3, w.x, acc[3][0]);
        acc[3][1] = fmaf(a3, w.y, acc[3][1]);
        acc[3][2] = fmaf(a3, w.z, acc[3][2]);
        acc[3][3] = fmaf(a3, w.w, acc[3][3]);
    }
#pragma unroll
    for (int r = 0; r < 4; r++) {
        int g = r0 + 4 * i + r;
        if (g < N) {
            float d = dinv[g];
            ((float4*)h2)[(size_t)g * 8 + j] =
                make_float4(acc[r][0] * d, acc[r][1] * d, acc[r][2] * d, acc[r][3] * d);
        }
    }
}

// ---- agg2: out = di*(Agg + self) + b2, unroll x4 -----------------------
__global__ __launch_bounds__(256) void k_agg2(const float* __restrict__ h2,
                                              const int* __restrict__ rowptr,
                                              const int2* __restrict__ csr,
                                              const float* __restrict__ dinv,
                                              const float* __restrict__ b2,
                                              float* __restrict__ out, int N) {
    int t = threadIdx.x;
    int lane = t & 63;
    int n = blockIdx.x * 4 + (t >> 6);
    if (n >= N) return;
    int g = lane >> 3;
    int l = lane & 7;
    int e0 = rowptr[n], e1 = rowptr[n + 1];
    float4 a0 = make_float4(0.f, 0.f, 0.f, 0.f);
    float4 a1 = make_float4(0.f, 0.f, 0.f, 0.f);
    float4 a2 = make_float4(0.f, 0.f, 0.f, 0.f);
    float4 a3 = make_float4(0.f, 0.f, 0.f, 0.f);
    int e = e0 + g;
    for (; e + 24 < e1; e += 32) {
        int2 c0 = csr[e];
        int2 c1 = csr[e + 8];
        int2 c2 = csr[e + 16];
        int2 c3 = csr[e + 24];
        float4 v0 = ((const float4*)(h2 + (size_t)c0.x * NCLS))[l];
        float4 v1 = ((const float4*)(h2 + (size_t)c1.x * NCLS))[l];
        float4 v2 = ((const float4*)(h2 + (size_t)c2.x * NCLS))[l];
        float4 v3 = ((const float4*)(h2 + (size_t)c3.x * NCLS))[l];
        float w0 = __int_as_float(c0.y), w1 = __int_as_float(c1.y);
        float w2 = __int_as_float(c2.y), w3 = __int_as_float(c3.y);
        a0.x = fmaf(w0, v0.x, a0.x); a0.y = fmaf(w0, v0.y, a0.y);
        a0.z = fmaf(w0, v0.z, a0.z); a0.w = fmaf(w0, v0.w, a0.w);
        a1.x = fmaf(w1, v1.x, a1.x); a1.y = fmaf(w1, v1.y, a1.y);
        a1.z = fmaf(w1, v1.z, a1.z); a1.w = fmaf(w1, v1.w, a1.w);
        a2.x = fmaf(w2, v2.x, a2.x); a2.y = fmaf(w2, v2.y, a2.y);
        a2.z = fmaf(w2, v2.z, a2.z); a2.w = fmaf(w2, v2.w, a2.w);
        a3.x = fmaf(w3, v3.x, a3.x); a3.y = fmaf(w3, v3.y, a3.y);
        a3.z = fmaf(w3, v3.z, a3.z); a3.w = fmaf(w3, v3.w, a3.w);
    }
    for (; e < e1; e += 8) {
        int2 c0 = csr[e];
        float4 v0 = ((const float4*)(h2 + (size_t)c0.x * NCLS))[l];
        float w0 = __int_as_float(c0.y);
        a0.x = fmaf(w0, v0.x, a0.x); a0.y = fmaf(w0, v0.y, a0.y);
        a0.z = fmaf(w0, v0.z, a0.z); a0.w = fmaf(w0, v0.w, a0.w);
    }
    a0.x += a1.x + a2.x + a3.x;
    a0.y += a1.y + a2.y + a3.y;
    a0.z += a1.z + a2.z + a3.z;
    a0.w += a1.w + a2.w + a3.w;
#pragma unroll
    for (int off = 8; off < 64; off <<= 1) {
        a0.x += __shfl_xor(a0.x, off, 64);
        a0.y += __shfl_xor(a0.y, off, 64);
        a0.z += __shfl_xor(a0.z, off, 64);
        a0.w += __shfl_xor(a0.w, off, 64);
    }
    if (lane < 8) {
        float di = dinv[n];
        float4 sv = ((const float4*)(h2 + (size_t)n * NCLS))[l];
        float4 bv = ((const float4*)b2)[l];
        float4 r;
        r.x = fmaf(di, a0.x + sv.x, bv.x);
        r.y = fmaf(di, a0.y + sv.y, bv.y);
        r.z = fmaf(di, a0.z + sv.z, bv.z);
        r.w = fmaf(di, a0.w + sv.w, bv.w);
        ((float4*)(out + (size_t)n * NCLS))[l] = r;
    }
}

extern "C" void kernel_launch(void* const* d_in, const int* in_sizes, int n_in,
                              void* d_out, int out_size, void* d_ws, size_t ws_size,
                              hipStream_t stream) {
    const float* x   = (const float*)d_in[0];
    const int*   ei  = (const int*)d_in[1];     // [2, E] int32
    const float* A0  = (const float*)d_in[2];
    const float* A1  = (const float*)d_in[3];
    const float* wsv = (const float*)d_in[4];
    const float* W1  = (const float*)d_in[5];
    const float* b1  = (const float*)d_in[6];
    const float* W2  = (const float*)d_in[7];
    const float* b2  = (const float*)d_in[8];
    float* out = (float*)d_out;

    int N = in_sizes[0] / NFEAT;    // 100000
    int E = in_sizes[1] / 2;        // 3200000
    const int* rowv = ei;           // source
    const int* colv = ei + E;       // target

    char* p = (char*)d_ws;
    auto alloc = [&](size_t bytes) -> void* {
        void* q = (void*)p; p += (bytes + 255) & ~(size_t)255; return q;
    };
    float* dinv    = (float*)alloc((size_t)N * 4);
    int*   rowptr  = (int*)  alloc((size_t)(N + 1) * 4);
    int*   colsum  = (int*)  alloc((size_t)NBKT * 4);
    int*   boff    = (int*)  alloc((size_t)(NBKT + 1) * 4);
    int*   hist    = (int*)  alloc((size_t)NBLK * NBKT * 4);   // 2.45 MB
    int2*  bin     = (int2*) alloc((size_t)E * 8);             // 25.6 MB
    int2*  csr     = (int2*) alloc((size_t)E * 8);             // 25.6 MB
    float* h0      = (float*)alloc((size_t)N * NHID * 4);      // 25.6 MB
    float* h       = (float*)alloc((size_t)N * NHID * 4);      // 25.6 MB
    float* h2      = h0;            // reuse: h0 dead after agg1

    int nblk = (E + EPB - 1) / EPB;     // == NBLK == 782

    k_count<<<nblk, 256, 0, stream>>>(colv, hist, E);
    k_colsum<<<NBKT, 1024, 0, stream>>>(hist, colsum);
    k_bscan<<<1, 1024, 0, stream>>>(colsum, boff);
    k_scatter<<<nblk, 256, 0, stream>>>(rowv, colv, A0, A1, wsv, hist, boff, bin, E);
    k_build<<<NBKT, 256, 0, stream>>>(bin, boff, rowptr, dinv, csr, N, E);
    k_gemm1<<<(N + 63) / 64, 256, 0, stream>>>(x, W1, dinv, h0, N);
    k_agg1<<<(N + 3) / 4, 256, 0, stream>>>(h0, rowptr, csr, dinv, b1, h, N);
    k_gemm2<<<(N + 63) / 64, 128, 0, stream>>>(h, W2, dinv, h2, N);
    k_agg2<<<(N + 3) / 4, 256, 0, stream>>>(h2, rowptr, csr, dinv, b2, out, N);
}

// Round 9
// 429.790 us; speedup vs baseline: 1.9715x; 1.1459x over previous
//
#include <hip/hip_runtime.h>
#include <hip/hip_fp16.h>

#define NFEAT 128
#define NHID  64
#define NCLS  32

#define RSH   7                 // 128 nodes per bucket
#define RNGB  128
#define NBKT  782               // ceil(100000 / 128)
#define EPB   4096              // edges per binning block
#define NBLK  782               // ceil(3200000 / 4096)

// ---- pass 1: per-block LDS histogram over 782 buckets ------------------
__global__ __launch_bounds__(256) void k_count(const int* __restrict__ colv,
                                               int* __restrict__ hist, int E) {
    __shared__ int lh[NBKT];
    int t = threadIdx.x, blk = blockIdx.x;
    for (int i = t; i < NBKT; i += 256) lh[i] = 0;
    __syncthreads();
    int e0 = blk * EPB, e1 = min(E, e0 + EPB);
    for (int e = e0 + t; e < e1; e += 256)
        atomicAdd(&lh[colv[e] >> RSH], 1);
    __syncthreads();
    int* row = hist + (size_t)blk * NBKT;
    for (int i = t; i < NBKT; i += 256) row[i] = lh[i];
}

// ---- pass 2: per-bucket exclusive scan over blocks (in place) ----------
__global__ __launch_bounds__(1024) void k_colsum(int* __restrict__ hist,
                                                 int* __restrict__ colsum) {
    __shared__ int s[1024];
    int t = threadIdx.x, b = blockIdx.x;
    int v = (t < NBLK) ? hist[(size_t)t * NBKT + b] : 0;
    s[t] = v; __syncthreads();
    for (int off = 1; off < 1024; off <<= 1) {
        int y = (t >= off) ? s[t - off] : 0;
        __syncthreads();
        s[t] += y;
        __syncthreads();
    }
    if (t < NBLK) hist[(size_t)t * NBKT + b] = s[t] - v;    // exclusive
    if (t == NBLK - 1) colsum[b] = s[t];
}

// ---- pass 3: exclusive scan of 782 bucket totals -> boff ---------------
__global__ void k_bscan(const int* __restrict__ colsum, int* __restrict__ boff) {
    __shared__ int s[1024];
    int t = threadIdx.x;
    int v = (t < NBKT) ? colsum[t] : 0;
    s[t] = v; __syncthreads();
    for (int off = 1; off < 1024; off <<= 1) {
        int y = (t >= off) ? s[t - off] : 0;
        __syncthreads();
        s[t] += y;
        __syncthreads();
    }
    if (t < NBKT) boff[t] = s[t] - v;
    if (t == 1023) boff[NBKT] = s[1023];
}

// ---- pass 4: scatter into exact bucket-sorted positions (LDS ranks) ----
__global__ __launch_bounds__(256) void k_scatter(const int* __restrict__ rowv,
                                                 const int* __restrict__ colv,
                                                 const float* __restrict__ A0,
                                                 const float* __restrict__ A1,
                                                 const float* __restrict__ wsv,
                                                 const int* __restrict__ hist,
                                                 const int* __restrict__ boff,
                                                 int2* __restrict__ bin, int E) {
    __shared__ int cur[NBKT];
    int t = threadIdx.x, blk = blockIdx.x;
    const int* row = hist + (size_t)blk * NBKT;
    for (int i = t; i < NBKT; i += 256) cur[i] = boff[i] + row[i];
    __syncthreads();
    int e0 = blk * EPB, e1 = min(E, e0 + EPB);
    float w0 = wsv[0], w1 = wsv[1];
    for (int e = e0 + t; e < e1; e += 256) {
        int c = colv[e];
        int b = c >> RSH;
        float ew = fmaf(w0, A0[e], w1 * A1[e]);
        int p = atomicAdd(&cur[b], 1);          // LDS returning
        int pk = ((c & (RNGB - 1)) << 17) | rowv[e];
        bin[p] = make_int2(pk, __float_as_int(ew));
    }
}

// ---- pass 5: per-bucket exact CSR + rowptr + dinv (LDS atomics only) ---
__global__ __launch_bounds__(256) void k_build(const int2* __restrict__ bin,
                                               const int* __restrict__ boff,
                                               int* __restrict__ rowptr,
                                               float* __restrict__ dinv,
                                               int2* __restrict__ csr,
                                               int N, int E) {
    __shared__ int   hist[RNGB];
    __shared__ int   cur[RNGB];
    __shared__ float fdeg[RNGB];
    __shared__ int   sc[RNGB];
    int b = blockIdx.x, t = threadIdx.x;
    int base = boff[b];
    int cnt = boff[b + 1] - base;
    if (t < RNGB) { hist[t] = 0; fdeg[t] = 0.f; }
    __syncthreads();
    const int2* mb = bin + base;
    for (int i = t; i < cnt; i += 256) {
        int2 v = mb[i];
        int co = v.x >> 17;
        atomicAdd(&hist[co], 1);
        atomicAdd(&fdeg[co], __int_as_float(v.y));
    }
    __syncthreads();
    if (t < RNGB) sc[t] = hist[t];
    __syncthreads();
    for (int off = 1; off < RNGB; off <<= 1) {
        int y = (t < RNGB && t >= off) ? sc[t - off] : 0;
        __syncthreads();
        if (t < RNGB) sc[t] += y;
        __syncthreads();
    }
    int node0 = b << RSH;
    if (t < RNGB) {
        int ex = sc[t] - hist[t];               // exclusive prefix
        cur[t] = ex;
        int node = node0 + t;
        if (node < N) {
            rowptr[node] = base + ex;
            dinv[node] = rsqrtf(1.0f + fdeg[t]);
        }
    }
    if (b == NBKT - 1 && t == 0) rowptr[N] = E;
    __syncthreads();
    for (int i = t; i < cnt; i += 256) {
        int2 v = mb[i];
        int co = v.x >> 17;
        int r = v.x & 0x1FFFF;
        int p = atomicAdd(&cur[co], 1);         // LDS rank
        csr[base + p] = make_int2(r, v.y);
    }
}

// ---- GEMM1 (register-tiled): h0' = fp16( dinv[r]*(x @ W1) ) ------------
__global__ __launch_bounds__(256) void k_gemm1(const float* __restrict__ x,
                                               const float* __restrict__ W1,
                                               const float* __restrict__ dinv,
                                               __half* __restrict__ h0, int N) {
    __shared__ float xs[64 * 132];      // 64 rows x (128 + 4 pad)
    __shared__ float ws[128 * 64];
    int t = threadIdx.x;
    int r0 = blockIdx.x * 64;
    {
        const float4* W4 = (const float4*)W1;
        float4* w4 = (float4*)ws;
#pragma unroll
        for (int i = 0; i < 8; i++) w4[t + 256 * i] = W4[t + 256 * i];
    }
#pragma unroll
    for (int m = 0; m < 8; m++) {
        int idx = t + 256 * m;          // 0..2047
        int row = idx >> 5, k4 = idx & 31;
        int g = r0 + row;
        float4 v = make_float4(0.f, 0.f, 0.f, 0.f);
        if (g < N) v = ((const float4*)x)[(size_t)g * 32 + k4];
        *(float4*)&xs[row * 132 + k4 * 4] = v;
    }
    __syncthreads();
    int i = t >> 4, j = t & 15;
    float acc[4][4] = {};
    const float* xr = &xs[(4 * i) * 132];
    const float* wc = &ws[4 * j];
#pragma unroll 4
    for (int k = 0; k < 128; k++) {
        float a0 = xr[k], a1 = xr[132 + k], a2 = xr[264 + k], a3 = xr[396 + k];
        float4 w = *(const float4*)&wc[k * 64];
        acc[0][0] = fmaf(a0, w.x, acc[0][0]);
        acc[0][1] = fmaf(a0, w.y, acc[0][1]);
        acc[0][2] = fmaf(a0, w.z, acc[0][2]);
        acc[0][3] = fmaf(a0, w.w, acc[0][3]);
        acc[1][0] = fmaf(a1, w.x, acc[1][0]);
        acc[1][1] = fmaf(a1, w.y, acc[1][1]);
        acc[1][2] = fmaf(a1, w.z, acc[1][2]);
        acc[1][3] = fmaf(a1, w.w, acc[1][3]);
        acc[2][0] = fmaf(a2, w.x, acc[2][0]);
        acc[2][1] = fmaf(a2, w.y, acc[2][1]);
        acc[2][2] = fmaf(a2, w.z, acc[2][2]);
        acc[2][3] = fmaf(a2, w.w, acc[2][3]);
        acc[3][0] = fmaf(a3, w.x, acc[3][0]);
        acc[3][1] = fmaf(a3, w.y, acc[3][1]);
        acc[3][2] = fmaf(a3, w.z, acc[3][2]);
        acc[3][3] = fmaf(a3, w.w, acc[3][3]);
    }
#pragma unroll
    for (int r = 0; r < 4; r++) {
        int g = r0 + 4 * i + r;
        if (g < N) {
            float d = dinv[g];
            __half2 p0 = __floats2half2_rn(acc[r][0] * d, acc[r][1] * d);
            __half2 p1 = __floats2half2_rn(acc[r][2] * d, acc[r][3] * d);
            uint2 pk;
            pk.x = *(unsigned int*)&p0;
            pk.y = *(unsigned int*)&p1;
            ((uint2*)h0)[(size_t)g * 16 + j] = pk;
        }
    }
}

// ---- agg1 + relu (fp16 gather): h = relu(di*(Agg + self) + b1) ---------
// wave per node. g = lane>>3: 8 edges per VMEM instr; l = lane&7: half8
// (16 B) chunk of the 64-half row. Unroll x2 -> 16 edges in flight.
__global__ __launch_bounds__(256) void k_agg1(const __half* __restrict__ h0,
                                              const int* __restrict__ rowptr,
                                              const int2* __restrict__ csr,
                                              const float* __restrict__ dinv,
                                              const float* __restrict__ b1,
                                              float* __restrict__ h, int N) {
    int t = threadIdx.x;
    int lane = t & 63;
    int n = blockIdx.x * 4 + (t >> 6);
    if (n >= N) return;
    int g = lane >> 3;
    int l = lane & 7;
    int e0 = rowptr[n], e1 = rowptr[n + 1];
    float a0[8] = {}, a1[8] = {};
    int e = e0 + g;
    for (; e + 8 < e1; e += 16) {
        int2 c0 = csr[e];
        int2 c1 = csr[e + 8];
        uint4 u0 = ((const uint4*)(h0 + (size_t)c0.x * NHID))[l];
        uint4 u1 = ((const uint4*)(h0 + (size_t)c1.x * NHID))[l];
        float w0 = __int_as_float(c0.y);
        float w1 = __int_as_float(c1.y);
        const __half2* p0 = (const __half2*)&u0;
        const __half2* p1 = (const __half2*)&u1;
#pragma unroll
        for (int k = 0; k < 4; k++) {
            float2 f0 = __half22float2(p0[k]);
            float2 f1 = __half22float2(p1[k]);
            a0[2 * k]     = fmaf(w0, f0.x, a0[2 * k]);
            a0[2 * k + 1] = fmaf(w0, f0.y, a0[2 * k + 1]);
            a1[2 * k]     = fmaf(w1, f1.x, a1[2 * k]);
            a1[2 * k + 1] = fmaf(w1, f1.y, a1[2 * k + 1]);
        }
    }
    if (e < e1) {
        int2 c0 = csr[e];
        uint4 u0 = ((const uint4*)(h0 + (size_t)c0.x * NHID))[l];
        float w0 = __int_as_float(c0.y);
        const __half2* p0 = (const __half2*)&u0;
#pragma unroll
        for (int k = 0; k < 4; k++) {
            float2 f0 = __half22float2(p0[k]);
            a0[2 * k]     = fmaf(w0, f0.x, a0[2 * k]);
            a0[2 * k + 1] = fmaf(w0, f0.y, a0[2 * k + 1]);
        }
    }
#pragma unroll
    for (int k = 0; k < 8; k++) a0[k] += a1[k];
#pragma unroll
    for (int off = 8; off < 64; off <<= 1) {
#pragma unroll
        for (int k = 0; k < 8; k++) a0[k] += __shfl_xor(a0[k], off, 64);
    }
    if (lane < 8) {
        float di = dinv[n];
        uint4 us = ((const uint4*)(h0 + (size_t)n * NHID))[l];
        const __half2* ps = (const __half2*)&us;
        float4 bv0 = ((const float4*)b1)[2 * l];
        float4 bv1 = ((const float4*)b1)[2 * l + 1];
        float bb[8] = {bv0.x, bv0.y, bv0.z, bv0.w, bv1.x, bv1.y, bv1.z, bv1.w};
        float r[8];
#pragma unroll
        for (int k = 0; k < 4; k++) {
            float2 s = __half22float2(ps[k]);
            r[2 * k]     = fmaxf(fmaf(di, a0[2 * k] + s.x, bb[2 * k]), 0.f);
            r[2 * k + 1] = fmaxf(fmaf(di, a0[2 * k + 1] + s.y, bb[2 * k + 1]), 0.f);
        }
        float4* hp = (float4*)(h + (size_t)n * NHID + l * 8);
        hp[0] = make_float4(r[0], r[1], r[2], r[3]);
        hp[1] = make_float4(r[4], r[5], r[6], r[7]);
    }
}

// ---- GEMM2 (register-tiled): h2' = fp16( dinv[r]*(h @ W2) ) ------------
__global__ __launch_bounds__(128) void k_gemm2(const float* __restrict__ h,
                                               const float* __restrict__ W2,
                                               const float* __restrict__ dinv,
                                               __half* __restrict__ h2, int N) {
    __shared__ float hs[64 * 68];   // 64 rows x (64 + 4 pad)
    __shared__ float ws[64 * 32];
    int t = threadIdx.x;
    int r0 = blockIdx.x * 64;
    {
        const float4* W4 = (const float4*)W2;
        float4* w4 = (float4*)ws;
#pragma unroll
        for (int i = 0; i < 4; i++) w4[t + 128 * i] = W4[t + 128 * i];
    }
#pragma unroll
    for (int m = 0; m < 8; m++) {
        int idx = t + 128 * m;          // 0..1023
        int row = idx >> 4, k4 = idx & 15;
        int g = r0 + row;
        float4 v = make_float4(0.f, 0.f, 0.f, 0.f);
        if (g < N) v = ((const float4*)h)[(size_t)g * 16 + k4];
        *(float4*)&hs[row * 68 + k4 * 4] = v;
    }
    __syncthreads();
    int i = t >> 3, j = t & 7;
    float acc[4][4] = {};
    const float* hr = &hs[(4 * i) * 68];
    const float* wc = &ws[4 * j];
#pragma unroll 4
    for (int k = 0; k < 64; k++) {
        float a0 = hr[k], a1 = hr[68 + k], a2 = hr[136 + k], a3 = hr[204 + k];
        float4 w = *(const float4*)&wc[k * 32];
        acc[0][0] = fmaf(a0, w.x, acc[0][0]);
        acc[0][1] = fmaf(a0, w.y, acc[0][1]);
        acc[0][2] = fmaf(a0, w.z, acc[0][2]);
        acc[0][3] = fmaf(a0, w.w, acc[0][3]);
        acc[1][0] = fmaf(a1, w.x, acc[1][0]);
        acc[1][1] = fmaf(a1, w.y, acc[1][1]);
        acc[1][2] = fmaf(a1, w.z, acc[1][2]);
        acc[1][3] = fmaf(a1, w.w, acc[1][3]);
        acc[2][0] = fmaf(a2, w.x, acc[2][0]);
        acc[2][1] = fmaf(a2, w.y, acc[2][1]);
        acc[2][2] = fmaf(a2, w.z, acc[2][2]);
        acc[2][3] = fmaf(a2, w.w, acc[2][3]);
        acc[3][0] = fmaf(a3, w.x, acc[3][0]);
        acc[3][1] = fmaf(a3, w.y, acc[3][1]);
        acc[3][2] = fmaf(a3, w.z, acc[3][2]);
        acc[3][3] = fmaf(a3, w.w, acc[3][3]);
    }
#pragma unroll
    for (int r = 0; r < 4; r++) {
        int g = r0 + 4 * i + r;
        if (g < N) {
            float d = dinv[g];
            __half2 p0 = __floats2half2_rn(acc[r][0] * d, acc[r][1] * d);
            __half2 p1 = __floats2half2_rn(acc[r][2] * d, acc[r][3] * d);
            uint2 pk;
            pk.x = *(unsigned int*)&p0;
            pk.y = *(unsigned int*)&p1;
            ((uint2*)h2)[(size_t)g * 8 + j] = pk;
        }
    }
}

// ---- agg2 (fp16 gather): out = di*(Agg + self) + b2 --------------------
// wave per node. g = lane>>2: 16 edges per VMEM instr; l = lane&3: half8
// (16 B) chunk of the 32-half row. Unroll x2 -> 32 edges in flight.
__global__ __launch_bounds__(256) void k_agg2(const __half* __restrict__ h2,
                                              const int* __restrict__ rowptr,
                                              const int2* __restrict__ csr,
                                              const float* __restrict__ dinv,
                                              const float* __restrict__ b2,
                                              float* __restrict__ out, int N) {
    int t = threadIdx.x;
    int lane = t & 63;
    int n = blockIdx.x * 4 + (t >> 6);
    if (n >= N) return;
    int g = lane >> 2;
    int l = lane & 3;
    int e0 = rowptr[n], e1 = rowptr[n + 1];
    float a0[8] = {}, a1[8] = {};
    int e = e0 + g;
    for (; e + 16 < e1; e += 32) {
        int2 c0 = csr[e];
        int2 c1 = csr[e + 16];
        uint4 u0 = ((const uint4*)(h2 + (size_t)c0.x * NCLS))[l];
        uint4 u1 = ((const uint4*)(h2 + (size_t)c1.x * NCLS))[l];
        float w0 = __int_as_float(c0.y);
        float w1 = __int_as_float(c1.y);
        const __half2* p0 = (const __half2*)&u0;
        const __half2* p1 = (const __half2*)&u1;
#pragma unroll
        for (int k = 0; k < 4; k++) {
            float2 f0 = __half22float2(p0[k]);
            float2 f1 = __half22float2(p1[k]);
            a0[2 * k]     = fmaf(w0, f0.x, a0[2 * k]);
            a0[2 * k + 1] = fmaf(w0, f0.y, a0[2 * k + 1]);
            a1[2 * k]     = fmaf(w1, f1.x, a1[2 * k]);
            a1[2 * k + 1] = fmaf(w1, f1.y, a1[2 * k + 1]);
        }
    }
    if (e < e1) {
        int2 c0 = csr[e];
        uint4 u0 = ((const uint4*)(h2 + (size_t)c0.x * NCLS))[l];
        float w0 = __int_as_float(c0.y);
        const __half2* p0 = (const __half2*)&u0;
#pragma unroll
        for (int k = 0; k < 4; k++) {
            float2 f0 = __half22float2(p0[k]);
            a0[2 * k]     = fmaf(w0, f0.x, a0[2 * k]);
            a0[2 * k + 1] = fmaf(w0, f0.y, a0[2 * k + 1]);
        }
    }
#pragma unroll
    for (int k = 0; k < 8; k++) a0[k] += a1[k];
#pragma unroll
    for (int off = 4; off < 64; off <<= 1) {
#pragma unroll
        for (int k = 0; k < 8; k++) a0[k] += __shfl_xor(a0[k], off, 64);
    }
    if (lane < 4) {
        float di = dinv[n];
        uint4 us = ((const uint4*)(h2 + (size_t)n * NCLS))[l];
        const __half2* ps = (const __half2*)&us;
        float4 bv0 = ((const float4*)b2)[2 * l];
        float4 bv1 = ((const float4*)b2)[2 * l + 1];
        float bb[8] = {bv0.x, bv0.y, bv0.z, bv0.w, bv1.x, bv1.y, bv1.z, bv1.w};
        float r[8];
#pragma unroll
        for (int k = 0; k < 4; k++) {
            float2 s = __half22float2(ps[k]);
            r[2 * k]     = fmaf(di, a0[2 * k] + s.x, bb[2 * k]);
            r[2 * k + 1] = fmaf(di, a0[2 * k + 1] + s.y, bb[2 * k + 1]);
        }
        float4* op = (float4*)(out + (size_t)n * NCLS + l * 8);
        op[0] = make_float4(r[0], r[1], r[2], r[3]);
        op[1] = make_float4(r[4], r[5], r[6], r[7]);
    }
}

extern "C" void kernel_launch(void* const* d_in, const int* in_sizes, int n_in,
                              void* d_out, int out_size, void* d_ws, size_t ws_size,
                              hipStream_t stream) {
    const float* x   = (const float*)d_in[0];
    const int*   ei  = (const int*)d_in[1];     // [2, E] int32
    const float* A0  = (const float*)d_in[2];
    const float* A1  = (const float*)d_in[3];
    const float* wsv = (const float*)d_in[4];
    const float* W1  = (const float*)d_in[5];
    const float* b1  = (const float*)d_in[6];
    const float* W2  = (const float*)d_in[7];
    const float* b2  = (const float*)d_in[8];
    float* out = (float*)d_out;

    int N = in_sizes[0] / NFEAT;    // 100000
    int E = in_sizes[1] / 2;        // 3200000
    const int* rowv = ei;           // source
    const int* colv = ei + E;       // target

    char* p = (char*)d_ws;
    auto alloc = [&](size_t bytes) -> void* {
        void* q = (void*)p; p += (bytes + 255) & ~(size_t)255; return q;
    };
    float*  dinv    = (float*)alloc((size_t)N * 4);
    int*    rowptr  = (int*)  alloc((size_t)(N + 1) * 4);
    int*    colsum  = (int*)  alloc((size_t)NBKT * 4);
    int*    boff    = (int*)  alloc((size_t)(NBKT + 1) * 4);
    int*    hist    = (int*)  alloc((size_t)NBLK * NBKT * 4);   // 2.45 MB
    int2*   bin     = (int2*) alloc((size_t)E * 8);             // 25.6 MB
    int2*   csr     = (int2*) alloc((size_t)E * 8);             // 25.6 MB
    __half* h0      = (__half*)alloc((size_t)N * NHID * 2);     // 12.8 MB
    float*  h       = (float*)alloc((size_t)N * NHID * 4);      // 25.6 MB
    __half* h2      = (__half*)alloc((size_t)N * NCLS * 2);     // 6.4 MB

    int nblk = (E + EPB - 1) / EPB;     // == NBLK == 782

    k_count<<<nblk, 256, 0, stream>>>(colv, hist, E);
    k_colsum<<<NBKT, 1024, 0, stream>>>(hist, colsum);
    k_bscan<<<1, 1024, 0, stream>>>(colsum, boff);
    k_scatter<<<nblk, 256, 0, stream>>>(rowv, colv, A0, A1, wsv, hist, boff, bin, E);
    k_build<<<NBKT, 256, 0, stream>>>(bin, boff, rowptr, dinv, csr, N, E);
    k_gemm1<<<(N + 63) / 64, 256, 0, stream>>>(x, W1, dinv, h0, N);
    k_agg1<<<(N + 3) / 4, 256, 0, stream>>>(h0, rowptr, csr, dinv, b1, h, N);
    k_gemm2<<<(N + 63) / 64, 128, 0, stream>>>(h, W2, dinv, h2, N);
    k_agg2<<<(N + 3) / 4, 256, 0, stream>>>(h2, rowptr, csr, dinv, b2, out, N);
}

// Round 10
// 404.373 us; speedup vs baseline: 2.0954x; 1.0629x over previous
//
#include <hip/hip_runtime.h>
#include <hip/hip_fp16.h>

#define NFEAT 128
#define NHID  64
#define NCLS  32

#define RSH   7                 // 128 nodes per bucket
#define RNGB  128
#define NBKT  782               // ceil(100000 / 128)
#define EPB   4096              // edges per binning block
#define NBLK  782               // ceil(3200000 / 4096)
#define BCAP2 6144              // k_build staging cap (mean 4096, sigma 64)

// ---- pass 1: per-block LDS histogram over 782 buckets ------------------
__global__ __launch_bounds__(256) void k_count(const int* __restrict__ colv,
                                               int* __restrict__ hist, int E) {
    __shared__ int lh[NBKT];
    int t = threadIdx.x, blk = blockIdx.x;
    for (int i = t; i < NBKT; i += 256) lh[i] = 0;
    __syncthreads();
    int e0 = blk * EPB, e1 = min(E, e0 + EPB);
    for (int e = e0 + t; e < e1; e += 256)
        atomicAdd(&lh[colv[e] >> RSH], 1);
    __syncthreads();
    int* row = hist + (size_t)blk * NBKT;
    for (int i = t; i < NBKT; i += 256) row[i] = lh[i];
}

// ---- pass 2: per-bucket exclusive scan over blocks (in place) ----------
__global__ __launch_bounds__(1024) void k_colsum(int* __restrict__ hist,
                                                 int* __restrict__ colsum) {
    __shared__ int s[1024];
    int t = threadIdx.x, b = blockIdx.x;
    int v = (t < NBLK) ? hist[(size_t)t * NBKT + b] : 0;
    s[t] = v; __syncthreads();
    for (int off = 1; off < 1024; off <<= 1) {
        int y = (t >= off) ? s[t - off] : 0;
        __syncthreads();
        s[t] += y;
        __syncthreads();
    }
    if (t < NBLK) hist[(size_t)t * NBKT + b] = s[t] - v;    // exclusive
    if (t == NBLK - 1) colsum[b] = s[t];
}

// ---- pass 3: exclusive scan of 782 bucket totals -> boff ---------------
__global__ void k_bscan(const int* __restrict__ colsum, int* __restrict__ boff) {
    __shared__ int s[1024];
    int t = threadIdx.x;
    int v = (t < NBKT) ? colsum[t] : 0;
    s[t] = v; __syncthreads();
    for (int off = 1; off < 1024; off <<= 1) {
        int y = (t >= off) ? s[t - off] : 0;
        __syncthreads();
        s[t] += y;
        __syncthreads();
    }
    if (t < NBKT) boff[t] = s[t] - v;
    if (t == 1023) boff[NBKT] = s[1023];
}

// ---- pass 4: scatter, locally SORTED then coalesced write --------------
// phase1: ranks via LDS atomics (state in VGPRs). phase2: place into
// block-sorted LDS buffer + per-slot global dest. phase3: stream out —
// consecutive lanes hit consecutive destinations within each run.
__global__ __launch_bounds__(256) void k_scatter(const int* __restrict__ rowv,
                                                 const int* __restrict__ colv,
                                                 const float* __restrict__ A0,
                                                 const float* __restrict__ A1,
                                                 const float* __restrict__ wsv,
                                                 const int* __restrict__ hist,
                                                 const int* __restrict__ boff,
                                                 int2* __restrict__ bin, int E) {
    __shared__ int  lhist[NBKT];
    __shared__ int  lscan[NBKT];
    __shared__ int  dstart[NBKT];
    __shared__ int  lds[256];
    __shared__ int2 sbuf[EPB];          // 32 KB
    __shared__ int  sdst[EPB];          // 16 KB
    int t = threadIdx.x, blk = blockIdx.x;
    for (int i = t; i < NBKT; i += 256) lhist[i] = 0;
    __syncthreads();
    int e0 = blk * EPB, e1 = min(E, e0 + EPB);
    int cnt = e1 - e0;
    float w0 = wsv[0], w1 = wsv[1];
    int mypk[16]; float myew[16]; int mybr[16];
    int nit = 0;
    for (int e = e0 + t; e < e1; e += 256, nit++) {
        int c = colv[e];
        int b = c >> RSH;
        mypk[nit] = ((c & (RNGB - 1)) << 17) | rowv[e];
        myew[nit] = fmaf(w0, A0[e], w1 * A1[e]);
        int rank = atomicAdd(&lhist[b], 1);         // rank < 4096 -> 12 bits
        mybr[nit] = (b << 12) | rank;
    }
    __syncthreads();
    // exclusive scan lhist(782) -> lscan
    int base4 = t * 4;
    int v0 = 0, v1 = 0, v2 = 0, v3 = 0;
    if (base4 + 0 < NBKT) v0 = lhist[base4 + 0];
    if (base4 + 1 < NBKT) v1 = lhist[base4 + 1];
    if (base4 + 2 < NBKT) v2 = lhist[base4 + 2];
    if (base4 + 3 < NBKT) v3 = lhist[base4 + 3];
    int s = v0 + v1 + v2 + v3;
    lds[t] = s; __syncthreads();
    for (int off = 1; off < 256; off <<= 1) {
        int y = (t >= off) ? lds[t - off] : 0;
        __syncthreads();
        lds[t] += y;
        __syncthreads();
    }
    int run = lds[t] - s;
    if (base4 + 0 < NBKT) { lscan[base4 + 0] = run; run += v0; }
    if (base4 + 1 < NBKT) { lscan[base4 + 1] = run; run += v1; }
    if (base4 + 2 < NBKT) { lscan[base4 + 2] = run; run += v2; }
    if (base4 + 3 < NBKT) { lscan[base4 + 3] = run; run += v3; }
    const int* gh = hist + (size_t)blk * NBKT;
    for (int i = t; i < NBKT; i += 256) dstart[i] = boff[i] + gh[i];
    __syncthreads();
    // phase2: place sorted
    for (int it = 0; it < nit; it++) {
        int b = mybr[it] >> 12, rank = mybr[it] & 4095;
        int lp = lscan[b] + rank;
        sbuf[lp] = make_int2(mypk[it], __float_as_int(myew[it]));
        sdst[lp] = dstart[b] + rank;
    }
    __syncthreads();
    // phase3: coalesced-run write-out
    for (int i = t; i < cnt; i += 256) bin[sdst[i]] = sbuf[i];
}

// ---- pass 5: per-bucket CSR, LDS-staged then CONTIGUOUS write ----------
__global__ __launch_bounds__(256) void k_build(const int2* __restrict__ bin,
                                               const int* __restrict__ boff,
                                               int* __restrict__ rowptr,
                                               float* __restrict__ dinv,
                                               int2* __restrict__ csr,
                                               int N, int E) {
    __shared__ int   hist[RNGB];
    __shared__ int   sc[RNGB];
    __shared__ float fdeg[RNGB];
    __shared__ int2  sb[BCAP2];         // 48 KB
    int b = blockIdx.x, t = threadIdx.x;
    int base = boff[b];
    int cnt = boff[b + 1] - base;
    if (t < RNGB) { hist[t] = 0; fdeg[t] = 0.f; }
    __syncthreads();
    const int2* mb = bin + base;
    int2 mv[24]; int mr[24];
    int nit = 0;
    for (int i = t; i < cnt; i += 256, nit++) {
        int2 v = mb[i];
        int co = v.x >> 17;
        mv[nit] = v;
        mr[nit] = atomicAdd(&hist[co], 1);
        atomicAdd(&fdeg[co], __int_as_float(v.y));
    }
    __syncthreads();
    if (t < RNGB) sc[t] = hist[t];
    __syncthreads();
    for (int off = 1; off < RNGB; off <<= 1) {
        int y = (t < RNGB && t >= off) ? sc[t - off] : 0;
        __syncthreads();
        if (t < RNGB) sc[t] += y;
        __syncthreads();
    }
    int node0 = b << RSH;
    if (t < RNGB) {
        int ex = sc[t] - hist[t];               // exclusive prefix
        int node = node0 + t;
        if (node < N) {
            rowptr[node] = base + ex;
            dinv[node] = rsqrtf(1.0f + fdeg[t]);
        }
        sc[t] = ex;                             // keep exclusive for placement
    }
    if (b == NBKT - 1 && t == 0) rowptr[N] = E;
    __syncthreads();
    for (int it = 0; it < nit; it++) {
        int2 v = mv[it];
        int co = v.x >> 17;
        sb[sc[co] + mr[it]] = make_int2(v.x & 0x1FFFF, v.y);
    }
    __syncthreads();
    for (int i = t; i < cnt; i += 256) csr[base + i] = sb[i];   // contiguous
}

// ---- GEMM1 (register-tiled): h0' = fp16( dinv[r]*(x @ W1) ) ------------
__global__ __launch_bounds__(256) void k_gemm1(const float* __restrict__ x,
                                               const float* __restrict__ W1,
                                               const float* __restrict__ dinv,
                                               __half* __restrict__ h0, int N) {
    __shared__ float xs[64 * 132];      // 64 rows x (128 + 4 pad)
    __shared__ float ws[128 * 64];
    int t = threadIdx.x;
    int r0 = blockIdx.x * 64;
    {
        const float4* W4 = (const float4*)W1;
        float4* w4 = (float4*)ws;
#pragma unroll
        for (int i = 0; i < 8; i++) w4[t + 256 * i] = W4[t + 256 * i];
    }
#pragma unroll
    for (int m = 0; m < 8; m++) {
        int idx = t + 256 * m;          // 0..2047
        int row = idx >> 5, k4 = idx & 31;
        int g = r0 + row;
        float4 v = make_float4(0.f, 0.f, 0.f, 0.f);
        if (g < N) v = ((const float4*)x)[(size_t)g * 32 + k4];
        *(float4*)&xs[row * 132 + k4 * 4] = v;
    }
    __syncthreads();
    int i = t >> 4, j = t & 15;
    float acc[4][4] = {};
    const float* xr = &xs[(4 * i) * 132];
    const float* wc = &ws[4 * j];
#pragma unroll 4
    for (int k = 0; k < 128; k++) {
        float a0 = xr[k], a1 = xr[132 + k], a2 = xr[264 + k], a3 = xr[396 + k];
        float4 w = *(const float4*)&wc[k * 64];
        acc[0][0] = fmaf(a0, w.x, acc[0][0]);
        acc[0][1] = fmaf(a0, w.y, acc[0][1]);
        acc[0][2] = fmaf(a0, w.z, acc[0][2]);
        acc[0][3] = fmaf(a0, w.w, acc[0][3]);
        acc[1][0] = fmaf(a1, w.x, acc[1][0]);
        acc[1][1] = fmaf(a1, w.y, acc[1][1]);
        acc[1][2] = fmaf(a1, w.z, acc[1][2]);
        acc[1][3] = fmaf(a1, w.w, acc[1][3]);
        acc[2][0] = fmaf(a2, w.x, acc[2][0]);
        acc[2][1] = fmaf(a2, w.y, acc[2][1]);
        acc[2][2] = fmaf(a2, w.z, acc[2][2]);
        acc[2][3] = fmaf(a2, w.w, acc[2][3]);
        acc[3][0] = fmaf(a3, w.x, acc[3][0]);
        acc[3][1] = fmaf(a3, w.y, acc[3][1]);
        acc[3][2] = fmaf(a3, w.z, acc[3][2]);
        acc[3][3] = fmaf(a3, w.w, acc[3][3]);
    }
#pragma unroll
    for (int r = 0; r < 4; r++) {
        int g = r0 + 4 * i + r;
        if (g < N) {
            float d = dinv[g];
            __half2 p0 = __floats2half2_rn(acc[r][0] * d, acc[r][1] * d);
            __half2 p1 = __floats2half2_rn(acc[r][2] * d, acc[r][3] * d);
            uint2 pk;
            pk.x = *(unsigned int*)&p0;
            pk.y = *(unsigned int*)&p1;
            ((uint2*)h0)[(size_t)g * 16 + j] = pk;
        }
    }
}

// ---- agg1 + relu (fp16 gather): h = relu(di*(Agg + self) + b1) ---------
__global__ __launch_bounds__(256) void k_agg1(const __half* __restrict__ h0,
                                              const int* __restrict__ rowptr,
                                              const int2* __restrict__ csr,
                                              const float* __restrict__ dinv,
                                              const float* __restrict__ b1,
                                              float* __restrict__ h, int N) {
    int t = threadIdx.x;
    int lane = t & 63;
    int n = blockIdx.x * 4 + (t >> 6);
    if (n >= N) return;
    int g = lane >> 3;
    int l = lane & 7;
    int e0 = rowptr[n], e1 = rowptr[n + 1];
    float a0[8] = {}, a1[8] = {};
    int e = e0 + g;
    for (; e + 8 < e1; e += 16) {
        int2 c0 = csr[e];
        int2 c1 = csr[e + 8];
        uint4 u0 = ((const uint4*)(h0 + (size_t)c0.x * NHID))[l];
        uint4 u1 = ((const uint4*)(h0 + (size_t)c1.x * NHID))[l];
        float w0 = __int_as_float(c0.y);
        float w1 = __int_as_float(c1.y);
        const __half2* p0 = (const __half2*)&u0;
        const __half2* p1 = (const __half2*)&u1;
#pragma unroll
        for (int k = 0; k < 4; k++) {
            float2 f0 = __half22float2(p0[k]);
            float2 f1 = __half22float2(p1[k]);
            a0[2 * k]     = fmaf(w0, f0.x, a0[2 * k]);
            a0[2 * k + 1] = fmaf(w0, f0.y, a0[2 * k + 1]);
            a1[2 * k]     = fmaf(w1, f1.x, a1[2 * k]);
            a1[2 * k + 1] = fmaf(w1, f1.y, a1[2 * k + 1]);
        }
    }
    if (e < e1) {
        int2 c0 = csr[e];
        uint4 u0 = ((const uint4*)(h0 + (size_t)c0.x * NHID))[l];
        float w0 = __int_as_float(c0.y);
        const __half2* p0 = (const __half2*)&u0;
#pragma unroll
        for (int k = 0; k < 4; k++) {
            float2 f0 = __half22float2(p0[k]);
            a0[2 * k]     = fmaf(w0, f0.x, a0[2 * k]);
            a0[2 * k + 1] = fmaf(w0, f0.y, a0[2 * k + 1]);
        }
    }
#pragma unroll
    for (int k = 0; k < 8; k++) a0[k] += a1[k];
#pragma unroll
    for (int off = 8; off < 64; off <<= 1) {
#pragma unroll
        for (int k = 0; k < 8; k++) a0[k] += __shfl_xor(a0[k], off, 64);
    }
    if (lane < 8) {
        float di = dinv[n];
        uint4 us = ((const uint4*)(h0 + (size_t)n * NHID))[l];
        const __half2* ps = (const __half2*)&us;
        float4 bv0 = ((const float4*)b1)[2 * l];
        float4 bv1 = ((const float4*)b1)[2 * l + 1];
        float bb[8] = {bv0.x, bv0.y, bv0.z, bv0.w, bv1.x, bv1.y, bv1.z, bv1.w};
        float r[8];
#pragma unroll
        for (int k = 0; k < 4; k++) {
            float2 s = __half22float2(ps[k]);
            r[2 * k]     = fmaxf(fmaf(di, a0[2 * k] + s.x, bb[2 * k]), 0.f);
            r[2 * k + 1] = fmaxf(fmaf(di, a0[2 * k + 1] + s.y, bb[2 * k + 1]), 0.f);
        }
        float4* hp = (float4*)(h + (size_t)n * NHID + l * 8);
        hp[0] = make_float4(r[0], r[1], r[2], r[3]);
        hp[1] = make_float4(r[4], r[5], r[6], r[7]);
    }
}

// ---- GEMM2 (register-tiled): h2' = fp16( dinv[r]*(h @ W2) ) ------------
__global__ __launch_bounds__(128) void k_gemm2(const float* __restrict__ h,
                                               const float* __restrict__ W2,
                                               const float* __restrict__ dinv,
                                               __half* __restrict__ h2, int N) {
    __shared__ float hs[64 * 68];   // 64 rows x (64 + 4 pad)
    __shared__ float ws[64 * 32];
    int t = threadIdx.x;
    int r0 = blockIdx.x * 64;
    {
        const float4* W4 = (const float4*)W2;
        float4* w4 = (float4*)ws;
#pragma unroll
        for (int i = 0; i < 4; i++) w4[t + 128 * i] = W4[t + 128 * i];
    }
#pragma unroll
    for (int m = 0; m < 8; m++) {
        int idx = t + 128 * m;          // 0..1023
        int row = idx >> 4, k4 = idx & 15;
        int g = r0 + row;
        float4 v = make_float4(0.f, 0.f, 0.f, 0.f);
        if (g < N) v = ((const float4*)h)[(size_t)g * 16 + k4];
        *(float4*)&hs[row * 68 + k4 * 4] = v;
    }
    __syncthreads();
    int i = t >> 3, j = t & 7;
    float acc[4][4] = {};
    const float* hr = &hs[(4 * i) * 68];
    const float* wc = &ws[4 * j];
#pragma unroll 4
    for (int k = 0; k < 64; k++) {
        float a0 = hr[k], a1 = hr[68 + k], a2 = hr[136 + k], a3 = hr[204 + k];
        float4 w = *(const float4*)&wc[k * 32];
        acc[0][0] = fmaf(a0, w.x, acc[0][0]);
        acc[0][1] = fmaf(a0, w.y, acc[0][1]);
        acc[0][2] = fmaf(a0, w.z, acc[0][2]);
        acc[0][3] = fmaf(a0, w.w, acc[0][3]);
        acc[1][0] = fmaf(a1, w.x, acc[1][0]);
        acc[1][1] = fmaf(a1, w.y, acc[1][1]);
        acc[1][2] = fmaf(a1, w.z, acc[1][2]);
        acc[1][3] = fmaf(a1, w.w, acc[1][3]);
        acc[2][0] = fmaf(a2, w.x, acc[2][0]);
        acc[2][1] = fmaf(a2, w.y, acc[2][1]);
        acc[2][2] = fmaf(a2, w.z, acc[2][2]);
        acc[2][3] = fmaf(a2, w.w, acc[2][3]);
        acc[3][0] = fmaf(a3, w.x, acc[3][0]);
        acc[3][1] = fmaf(a3, w.y, acc[3][1]);
        acc[3][2] = fmaf(a3, w.z, acc[3][2]);
        acc[3][3] = fmaf(a3, w.w, acc[3][3]);
    }
#pragma unroll
    for (int r = 0; r < 4; r++) {
        int g = r0 + 4 * i + r;
        if (g < N) {
            float d = dinv[g];
            __half2 p0 = __floats2half2_rn(acc[r][0] * d, acc[r][1] * d);
            __half2 p1 = __floats2half2_rn(acc[r][2] * d, acc[r][3] * d);
            uint2 pk;
            pk.x = *(unsigned int*)&p0;
            pk.y = *(unsigned int*)&p1;
            ((uint2*)h2)[(size_t)g * 8 + j] = pk;
        }
    }
}

// ---- agg2 (fp16 gather): out = di*(Agg + self) + b2 --------------------
__global__ __launch_bounds__(256) void k_agg2(const __half* __restrict__ h2,
                                              const int* __restrict__ rowptr,
                                              const int2* __restrict__ csr,
                                              const float* __restrict__ dinv,
                                              const float* __restrict__ b2,
                                              float* __restrict__ out, int N) {
    int t = threadIdx.x;
    int lane = t & 63;
    int n = blockIdx.x * 4 + (t >> 6);
    if (n >= N) return;
    int g = lane >> 2;
    int l = lane & 3;
    int e0 = rowptr[n], e1 = rowptr[n + 1];
    float a0[8] = {}, a1[8] = {};
    int e = e0 + g;
    for (; e + 16 < e1; e += 32) {
        int2 c0 = csr[e];
        int2 c1 = csr[e + 16];
        uint4 u0 = ((const uint4*)(h2 + (size_t)c0.x * NCLS))[l];
        uint4 u1 = ((const uint4*)(h2 + (size_t)c1.x * NCLS))[l];
        float w0 = __int_as_float(c0.y);
        float w1 = __int_as_float(c1.y);
        const __half2* p0 = (const __half2*)&u0;
        const __half2* p1 = (const __half2*)&u1;
#pragma unroll
        for (int k = 0; k < 4; k++) {
            float2 f0 = __half22float2(p0[k]);
            float2 f1 = __half22float2(p1[k]);
            a0[2 * k]     = fmaf(w0, f0.x, a0[2 * k]);
            a0[2 * k + 1] = fmaf(w0, f0.y, a0[2 * k + 1]);
            a1[2 * k]     = fmaf(w1, f1.x, a1[2 * k]);
            a1[2 * k + 1] = fmaf(w1, f1.y, a1[2 * k + 1]);
        }
    }
    if (e < e1) {
        int2 c0 = csr[e];
        uint4 u0 = ((const uint4*)(h2 + (size_t)c0.x * NCLS))[l];
        float w0 = __int_as_float(c0.y);
        const __half2* p0 = (const __half2*)&u0;
#pragma unroll
        for (int k = 0; k < 4; k++) {
            float2 f0 = __half22float2(p0[k]);
            a0[2 * k]     = fmaf(w0, f0.x, a0[2 * k]);
            a0[2 * k + 1] = fmaf(w0, f0.y, a0[2 * k + 1]);
        }
    }
#pragma unroll
    for (int k = 0; k < 8; k++) a0[k] += a1[k];
#pragma unroll
    for (int off = 4; off < 64; off <<= 1) {
#pragma unroll
        for (int k = 0; k < 8; k++) a0[k] += __shfl_xor(a0[k], off, 64);
    }
    if (lane < 4) {
        float di = dinv[n];
        uint4 us = ((const uint4*)(h2 + (size_t)n * NCLS))[l];
        const __half2* ps = (const __half2*)&us;
        float4 bv0 = ((const float4*)b2)[2 * l];
        float4 bv1 = ((const float4*)b2)[2 * l + 1];
        float bb[8] = {bv0.x, bv0.y, bv0.z, bv0.w, bv1.x, bv1.y, bv1.z, bv1.w};
        float r[8];
#pragma unroll
        for (int k = 0; k < 4; k++) {
            float2 s = __half22float2(ps[k]);
            r[2 * k]     = fmaf(di, a0[2 * k] + s.x, bb[2 * k]);
            r[2 * k + 1] = fmaf(di, a0[2 * k + 1] + s.y, bb[2 * k + 1]);
        }
        float4* op = (float4*)(out + (size_t)n * NCLS + l * 8);
        op[0] = make_float4(r[0], r[1], r[2], r[3]);
        op[1] = make_float4(r[4], r[5], r[6], r[7]);
    }
}

extern "C" void kernel_launch(void* const* d_in, const int* in_sizes, int n_in,
                              void* d_out, int out_size, void* d_ws, size_t ws_size,
                              hipStream_t stream) {
    const float* x   = (const float*)d_in[0];
    const int*   ei  = (const int*)d_in[1];     // [2, E] int32
    const float* A0  = (const float*)d_in[2];
    const float* A1  = (const float*)d_in[3];
    const float* wsv = (const float*)d_in[4];
    const float* W1  = (const float*)d_in[5];
    const float* b1  = (const float*)d_in[6];
    const float* W2  = (const float*)d_in[7];
    const float* b2  = (const float*)d_in[8];
    float* out = (float*)d_out;

    int N = in_sizes[0] / NFEAT;    // 100000
    int E = in_sizes[1] / 2;        // 3200000
    const int* rowv = ei;           // source
    const int* colv = ei + E;       // target

    char* p = (char*)d_ws;
    auto alloc = [&](size_t bytes) -> void* {
        void* q = (void*)p; p += (bytes + 255) & ~(size_t)255; return q;
    };
    float*  dinv    = (float*)alloc((size_t)N * 4);
    int*    rowptr  = (int*)  alloc((size_t)(N + 1) * 4);
    int*    colsum  = (int*)  alloc((size_t)NBKT * 4);
    int*    boff    = (int*)  alloc((size_t)(NBKT + 1) * 4);
    int*    hist    = (int*)  alloc((size_t)NBLK * NBKT * 4);   // 2.45 MB
    int2*   bin     = (int2*) alloc((size_t)E * 8);             // 25.6 MB
    int2*   csr     = (int2*) alloc((size_t)E * 8);             // 25.6 MB
    __half* h0      = (__half*)alloc((size_t)N * NHID * 2);     // 12.8 MB
    float*  h       = (float*)alloc((size_t)N * NHID * 4);      // 25.6 MB
    __half* h2      = (__half*)alloc((size_t)N * NCLS * 2);     // 6.4 MB

    int nblk = (E + EPB - 1) / EPB;     // == NBLK == 782

    k_count<<<nblk, 256, 0, stream>>>(colv, hist, E);
    k_colsum<<<NBKT, 1024, 0, stream>>>(hist, colsum);
    k_bscan<<<1, 1024, 0, stream>>>(colsum, boff);
    k_scatter<<<nblk, 256, 0, stream>>>(rowv, colv, A0, A1, wsv, hist, boff, bin, E);
    k_build<<<NBKT, 256, 0, stream>>>(bin, boff, rowptr, dinv, csr, N, E);
    k_gemm1<<<(N + 63) / 64, 256, 0, stream>>>(x, W1, dinv, h0, N);
    k_agg1<<<(N + 3) / 4, 256, 0, stream>>>(h0, rowptr, csr, dinv, b1, h, N);
    k_gemm2<<<(N + 63) / 64, 128, 0, stream>>>(h, W2, dinv, h2, N);
    k_agg2<<<(N + 3) / 4, 256, 0, stream>>>(h2, rowptr, csr, dinv, b2, out, N);
}